// Round 9
// baseline (556.129 us; speedup 1.0000x reference)
//
#include <hip/hip_runtime.h>
#include <math.h>

#define NROWS (512 * 512)   // B*T = 262144
#define KCB   1024          // codebook size
#define DDIM  64            // embedding dim
#define RPT   2             // rows per thread (hr=128 regs; RPT=4 spills — R3)
#define BLK   256           // threads per block
#define NQ    ((size_t)NROWS * DDIM)

// B_k = sum_i weight[k][i]^2, fp32, numpy pairwise-8 pattern (frozen — validated R2)
__global__ void wsq_kernel(const float* __restrict__ w, float* __restrict__ bsq) {
    int k = blockIdx.x * blockDim.x + threadIdx.x;
    if (k >= KCB) return;
    const float* row = w + (size_t)k * DDIM;
    float r[8];
#pragma unroll
    for (int j = 0; j < 8; ++j) r[j] = __fmul_rn(row[j], row[j]);
#pragma unroll
    for (int i = 8; i < DDIM; i += 8)
#pragma unroll
        for (int j = 0; j < 8; ++j)
            r[j] = __fadd_rn(r[j], __fmul_rn(row[i + j], row[i + j]));
    bsq[k] = __fadd_rn(__fadd_rn(__fadd_rn(r[0], r[1]), __fadd_rn(r[2], r[3])),
                       __fadd_rn(__fadd_rn(r[4], r[5]), __fadd_rn(r[6], r[7])));
}

// w feed rides the SCALAR pipe: wave-uniform rotating half-row buffers cA/cB
// (SGPR-resident), reloaded with the NEXT row right after their last use.
// v_fma_f32 takes the w operand directly from SGPR. No LDS, no k-loop VMEM.
__global__ __launch_bounds__(BLK, 2)
void vq_main(const float* __restrict__ h, const float* __restrict__ w,
             const float* __restrict__ bsq, float* __restrict__ out) {
    const int tid = threadIdx.x;
    const size_t rowbase = (size_t)blockIdx.x * (BLK * RPT) + (size_t)tid * RPT;

    // 2 h rows -> registers (128)
    float hr[RPT][DDIM];
#pragma unroll
    for (int r = 0; r < RPT; ++r) {
        const float* hrow = h + (rowbase + r) * DDIM;
#pragma unroll
        for (int i = 0; i < DDIM; i += 4) {
            float4 v = *reinterpret_cast<const float4*>(hrow + i);
            hr[r][i] = v.x; hr[r][i + 1] = v.y; hr[r][i + 2] = v.z; hr[r][i + 3] = v.w;
        }
    }

    // A_r = (h**2).sum per row, numpy pairwise-8 ordering (frozen — validated R2)
    float A[RPT];
#pragma unroll
    for (int r = 0; r < RPT; ++r) {
        float s[8];
#pragma unroll
        for (int j = 0; j < 8; ++j) s[j] = __fmul_rn(hr[r][j], hr[r][j]);
#pragma unroll
        for (int i = 8; i < DDIM; i += 8)
#pragma unroll
            for (int j = 0; j < 8; ++j)
                s[j] = __fadd_rn(s[j], __fmul_rn(hr[r][i + j], hr[r][i + j]));
        A[r] = __fadd_rn(__fadd_rn(__fadd_rn(s[0], s[1]), __fadd_rn(s[2], s[3])),
                         __fadd_rn(__fadd_rn(s[4], s[5]), __fadd_rn(s[6], s[7])));
    }

    float best[RPT];
    int bestk[RPT];
#pragma unroll
    for (int r = 0; r < RPT; ++r) { best[r] = INFINITY; bestk[r] = 0; }

    // uniform rotating half-row buffers (compiler scalarizes -> ~64 SGPRs)
    float cA[32], cB[32];
    {
        const float* w0 = w;            // row 0
#pragma unroll
        for (int j = 0; j < 32; ++j) cA[j] = w0[j];
#pragma unroll
        for (int j = 0; j < 32; ++j) cB[j] = w0[32 + j];
    }

#pragma unroll 1
    for (int k = 0; k < KCB; ++k) {
        // next row pointer (tail clamp: duplicate load, never consumed)
        const int kn = (k + 1 < KCB) ? (k + 1) : (KCB - 1);
        const float* wn = w + (size_t)kn * DDIM;

        float ac[RPT];
#pragma unroll
        for (int r = 0; r < RPT; ++r) ac[r] = 0.f;

        // chain part A: d0..31 from cA (d-ascending, single accumulator)
#pragma unroll
        for (int j = 0; j < 32; ++j)
#pragma unroll
            for (int r = 0; r < RPT; ++r)
                ac[r] = fmaf(hr[r][j], cA[j], ac[r]);

        // reload cA <- next row d0..31 (use is next iteration's part A)
#pragma unroll
        for (int j = 0; j < 32; ++j) cA[j] = wn[j];

        // chain part B: d32..63 from cB (same accumulator — full sequential chain)
#pragma unroll
        for (int j = 0; j < 32; ++j)
#pragma unroll
            for (int r = 0; r < RPT; ++r)
                ac[r] = fmaf(hr[r][32 + j], cB[j], ac[r]);

        // reload cB <- next row d32..63
#pragma unroll
        for (int j = 0; j < 32; ++j) cB[j] = wn[32 + j];

        // dist = fl(fl(A + B_k) - 2*acc); k-ascending first-min-wins (frozen)
        float b = bsq[k];               // uniform -> scalar pipe (4 KB, K$-resident)
#pragma unroll
        for (int r = 0; r < RPT; ++r) {
            float d = __fsub_rn(__fadd_rn(A[r], b), __fadd_rn(ac[r], ac[r]));
            if (d < best[r]) { best[r] = d; bestk[r] = k; }
        }
    }

    // ---- epilogue (all f32): qst = h + (q - h); loss; idx ---- (frozen — validated R2)
#pragma unroll
    for (int r = 0; r < RPT; ++r) {
        const size_t n = rowbase + r;
        const float* qrow = w + (size_t)bestk[r] * DDIM;   // per-lane -> VMEM gather
        float* qst = out + n * DDIM;
        float r2[8];
#pragma unroll
        for (int c = 0; c < 8; ++c) {
            float4 qa = *reinterpret_cast<const float4*>(qrow + 8 * c);
            float4 qb = *reinterpret_cast<const float4*>(qrow + 8 * c + 4);
            float d0 = __fsub_rn(qa.x, hr[r][8 * c + 0]);
            float d1 = __fsub_rn(qa.y, hr[r][8 * c + 1]);
            float d2 = __fsub_rn(qa.z, hr[r][8 * c + 2]);
            float d3 = __fsub_rn(qa.w, hr[r][8 * c + 3]);
            float d4 = __fsub_rn(qb.x, hr[r][8 * c + 4]);
            float d5 = __fsub_rn(qb.y, hr[r][8 * c + 5]);
            float d6 = __fsub_rn(qb.z, hr[r][8 * c + 6]);
            float d7 = __fsub_rn(qb.w, hr[r][8 * c + 7]);
            if (c == 0) {
                r2[0] = __fmul_rn(d0, d0); r2[1] = __fmul_rn(d1, d1);
                r2[2] = __fmul_rn(d2, d2); r2[3] = __fmul_rn(d3, d3);
                r2[4] = __fmul_rn(d4, d4); r2[5] = __fmul_rn(d5, d5);
                r2[6] = __fmul_rn(d6, d6); r2[7] = __fmul_rn(d7, d7);
            } else {
                r2[0] = __fadd_rn(r2[0], __fmul_rn(d0, d0));
                r2[1] = __fadd_rn(r2[1], __fmul_rn(d1, d1));
                r2[2] = __fadd_rn(r2[2], __fmul_rn(d2, d2));
                r2[3] = __fadd_rn(r2[3], __fmul_rn(d3, d3));
                r2[4] = __fadd_rn(r2[4], __fmul_rn(d4, d4));
                r2[5] = __fadd_rn(r2[5], __fmul_rn(d5, d5));
                r2[6] = __fadd_rn(r2[6], __fmul_rn(d6, d6));
                r2[7] = __fadd_rn(r2[7], __fmul_rn(d7, d7));
            }
            float4 oa, ob;
            oa.x = __fadd_rn(hr[r][8 * c + 0], d0);
            oa.y = __fadd_rn(hr[r][8 * c + 1], d1);
            oa.z = __fadd_rn(hr[r][8 * c + 2], d2);
            oa.w = __fadd_rn(hr[r][8 * c + 3], d3);
            ob.x = __fadd_rn(hr[r][8 * c + 4], d4);
            ob.y = __fadd_rn(hr[r][8 * c + 5], d5);
            ob.z = __fadd_rn(hr[r][8 * c + 6], d6);
            ob.w = __fadd_rn(hr[r][8 * c + 7], d7);
            *reinterpret_cast<float4*>(qst + 8 * c) = oa;
            *reinterpret_cast<float4*>(qst + 8 * c + 4) = ob;
        }
        float S = __fadd_rn(__fadd_rn(__fadd_rn(r2[0], r2[1]), __fadd_rn(r2[2], r2[3])),
                            __fadd_rn(__fadd_rn(r2[4], r2[5]), __fadd_rn(r2[6], r2[7])));
        float m = __fmul_rn(S, 0.015625f);
        float loss = __fadd_rn(__fmul_rn(m, 0.1f), __fmul_rn(m, 0.2f));
        out[NQ + n] = (float)bestk[r];
        out[NQ + NROWS + n] = loss;
    }
}

extern "C" void kernel_launch(void* const* d_in, const int* in_sizes, int n_in,
                              void* d_out, int out_size, void* d_ws, size_t ws_size,
                              hipStream_t stream) {
    (void)in_sizes; (void)n_in; (void)out_size; (void)ws_size;
    const float* h = (const float*)d_in[0];
    const float* w = (const float*)d_in[1];
    float* bsq = (float*)d_ws;
    float* out = (float*)d_out;

    wsq_kernel<<<(KCB + 255) / 256, 256, 0, stream>>>(w, bsq);
    vq_main<<<NROWS / (BLK * RPT), BLK, 0, stream>>>(h, w, bsq, out);
}

// Round 10
// 520.661 us; speedup vs baseline: 1.0681x; 1.0681x over previous
//
#include <hip/hip_runtime.h>
#include <math.h>

#define NROWS (512 * 512)
#define KCB   1024
#define DDIM  64
#define NQ    ((size_t)NROWS * DDIM)
#define RPB   32            // h-rows per block in main kernel
#define CMAX  64            // candidate list cap per row

typedef __attribute__((ext_vector_type(8))) short bf16x8;
typedef __attribute__((ext_vector_type(4))) float f32x4;

// bf16 RNE (matches ml_dtypes/hardware cvt for finite values)
__device__ __forceinline__ unsigned short f2bf(float x) {
    unsigned u = __float_as_uint(x);
    u = u + 0x7FFFu + ((u >> 16) & 1u);
    return (unsigned short)(u >> 16);
}
__device__ __forceinline__ float bfhi2f(unsigned u) {  // high 16 bits as bf16
    return __uint_as_float(u & 0xFFFF0000u);
}
__device__ __forceinline__ float bflo2f(unsigned u) {  // low 16 bits as bf16
    return __uint_as_float(u << 16);
}

// ---------- K1: frozen wsq + w->bf16 + wmax (single block, 1024 threads) ----------
__global__ __launch_bounds__(1024)
void prep_w(const float* __restrict__ w, float* __restrict__ bsq,
            unsigned short* __restrict__ wbf, float* __restrict__ wmaxp) {
    __shared__ float red[16];
    const int k = threadIdx.x;          // 0..1023
    const float* row = w + (size_t)k * DDIM;
    float r[8];
#pragma unroll
    for (int j = 0; j < 8; ++j) r[j] = __fmul_rn(row[j], row[j]);
#pragma unroll
    for (int i = 8; i < DDIM; i += 8)
#pragma unroll
        for (int j = 0; j < 8; ++j)
            r[j] = __fadd_rn(r[j], __fmul_rn(row[i + j], row[i + j]));
    float b = __fadd_rn(__fadd_rn(__fadd_rn(r[0], r[1]), __fadd_rn(r[2], r[3])),
                        __fadd_rn(__fadd_rn(r[4], r[5]), __fadd_rn(r[6], r[7])));
    bsq[k] = b;
    // bf16 copy of the row (packed dword stores)
    unsigned* dst = (unsigned*)(wbf + (size_t)k * DDIM);
#pragma unroll
    for (int j = 0; j < 32; ++j)
        dst[j] = (unsigned)f2bf(row[2 * j]) | ((unsigned)f2bf(row[2 * j + 1]) << 16);
    // wmax = max_k ||w_k|| (upper-bounded)
    float v = sqrtf(b) * 1.02f;
#pragma unroll
    for (int off = 1; off < 64; off <<= 1) v = fmaxf(v, __shfl_xor(v, off));
    if ((threadIdx.x & 63) == 0) red[threadIdx.x >> 6] = v;
    __syncthreads();
    if (threadIdx.x == 0) {
        float m = red[0];
#pragma unroll
        for (int j = 1; j < 16; ++j) m = fmaxf(m, red[j]);
        *wmaxp = m;
    }
}

// ---------- K2: frozen asq (numpy pairwise-8) ----------
__global__ __launch_bounds__(256)
void prep_h(const float* __restrict__ h, float* __restrict__ asq) {
    const size_t n = (size_t)blockIdx.x * 256 + threadIdx.x;
    const float* row = h + n * DDIM;
    float hr[DDIM];
#pragma unroll
    for (int i = 0; i < DDIM; i += 4) {
        float4 v = *reinterpret_cast<const float4*>(row + i);
        hr[i] = v.x; hr[i + 1] = v.y; hr[i + 2] = v.z; hr[i + 3] = v.w;
    }
    float s[8];
#pragma unroll
    for (int j = 0; j < 8; ++j) s[j] = __fmul_rn(hr[j], hr[j]);
#pragma unroll
    for (int i = 8; i < DDIM; i += 8)
#pragma unroll
        for (int j = 0; j < 8; ++j)
            s[j] = __fadd_rn(s[j], __fmul_rn(hr[i + j], hr[i + j]));
    asq[n] = __fadd_rn(__fadd_rn(__fadd_rn(s[0], s[1]), __fadd_rn(s[2], s[3])),
                       __fadd_rn(__fadd_rn(s[4], s[5]), __fadd_rn(s[6], s[7])));
}

// ---------- K3: MFMA scan + candidate + exact rescore; writes idx output ----------
__global__ __launch_bounds__(256, 2)
void vq_scan(const float* __restrict__ h, const float* __restrict__ w,
             const unsigned short* __restrict__ wbf, const float* __restrict__ bsq,
             const float* __restrict__ asq, const float* __restrict__ wmaxp,
             float* __restrict__ out) {
    __shared__ unsigned short sD[RPB * KCB];   // 64 KB: val = B_k - 2*dot (bf16)
    __shared__ int scnt[RPB];
    __shared__ int sclist[RPB][CMAX];

    const int tid = threadIdx.x;
    const int wv = tid >> 6, lane = tid & 63;
    const int l16 = lane & 15, lh = lane >> 4;        // entity idx / k-block
    const int rowbase = blockIdx.x * RPB;

    if (tid < RPB) scnt[tid] = 0;

    int vzero;                                        // keeps uniform loads on VMEM
    asm volatile("v_mov_b32 %0, 0" : "=v"(vzero));

    // ---- phase 1: A-frags (h rows, bf16) then MFMA over all 64 n-tiles ----
    bf16x8 afr[2][2];
#pragma unroll
    for (int mt = 0; mt < 2; ++mt) {
        const float* hrow = h + ((size_t)(rowbase + mt * 16 + l16)) * DDIM;
#pragma unroll
        for (int dh = 0; dh < 2; ++dh) {
            float4 a = *reinterpret_cast<const float4*>(hrow + dh * 32 + lh * 8);
            float4 bq = *reinterpret_cast<const float4*>(hrow + dh * 32 + lh * 8 + 4);
            union { bf16x8 v; unsigned short u[8]; } pk;
            pk.u[0] = f2bf(a.x); pk.u[1] = f2bf(a.y); pk.u[2] = f2bf(a.z); pk.u[3] = f2bf(a.w);
            pk.u[4] = f2bf(bq.x); pk.u[5] = f2bf(bq.y); pk.u[6] = f2bf(bq.z); pk.u[7] = f2bf(bq.w);
            afr[mt][dh] = pk.v;
        }
    }

#pragma unroll 2
    for (int nt = wv; nt < KCB / 16; nt += 4) {       // waves split the 64 n-tiles
        const unsigned short* wrow = wbf + (size_t)(nt * 16 + l16) * DDIM;
        bf16x8 bfr0 = *reinterpret_cast<const bf16x8*>(wrow + lh * 8);
        bf16x8 bfr1 = *reinterpret_cast<const bf16x8*>(wrow + 32 + lh * 8);
        float bq = bsq[nt * 16 + l16];
#pragma unroll
        for (int mt = 0; mt < 2; ++mt) {
            f32x4 acc = {0.f, 0.f, 0.f, 0.f};
            acc = __builtin_amdgcn_mfma_f32_16x16x32_bf16(afr[mt][0], bfr0, acc, 0, 0, 0);
            acc = __builtin_amdgcn_mfma_f32_16x16x32_bf16(afr[mt][1], bfr1, acc, 0, 0, 0);
#pragma unroll
            for (int i = 0; i < 4; ++i) {
                int rloc = mt * 16 + lh * 4 + i;      // C/D: row=(lane>>4)*4+reg, col=lane&15
                float val = bq - (acc[i] + acc[i]);   // approx: B_k - 2*dot
                sD[rloc * KCB + nt * 16 + l16] = f2bf(val);
            }
        }
    }
    __syncthreads();

    const float wmaxv = *wmaxp;

    // ---- phase 2: per-row min-scan, candidates, exact rescore (wave-private) ----
#pragma unroll 1
    for (int rr = 0; rr < RPB / 4; ++rr) {
        const int r = wv * (RPB / 4) + rr;
        const size_t n_glob = (size_t)rowbase + r;

        // h row fp32 for the exact chain (uniform addr kept on VMEM via vzero)
        const float* hrow = h + n_glob * DDIM + vzero;
        float hreg[DDIM];
#pragma unroll
        for (int i = 0; i < DDIM; i += 4) {
            float4 v = *reinterpret_cast<const float4*>(hrow + i);
            hreg[i] = v.x; hreg[i + 1] = v.y; hreg[i + 2] = v.z; hreg[i + 3] = v.w;
        }

        // scan 16 vals per lane (n = lane*16 + j)
        const unsigned* du = (const unsigned*)(sD + r * KCB + lane * 16);
        float sv[16];
#pragma unroll
        for (int q = 0; q < 8; ++q) {
            unsigned u = du[q];
            sv[2 * q] = bflo2f(u);
            sv[2 * q + 1] = bfhi2f(u);
        }
        float mn = sv[0];
#pragma unroll
        for (int j = 1; j < 16; ++j) mn = fminf(mn, sv[j]);
#pragma unroll
        for (int off = 1; off < 64; off <<= 1) mn = fminf(mn, __shfl_xor(mn, off));

        const float Af = asq[n_glob];
        const float hn = sqrtf(Af) * 1.001f;
        const float thr = mn + hn * wmaxv * 0.03125f + 1e-3f;   // 4x analytic + slack

#pragma unroll
        for (int j = 0; j < 16; ++j) {
            if (sv[j] <= thr) {
                int slot = atomicAdd(&scnt[r], 1);
                if (slot < CMAX) sclist[r][slot] = lane * 16 + j;
            }
        }
        int cntv = atomicAdd(&scnt[r], 0);   // ordered read-after-adds (wave-local row)

        // exact rescore (frozen chain, validated R2): candidates or full fallback
        float dbest = INFINITY;
        int kbest = 0x7FFFFFFF;
        if (cntv <= CMAX) {
            if (lane < cntv) {
                int k = sclist[r][lane];
                const float* wr = w + (size_t)k * DDIM;
                float acc = 0.f;
#pragma unroll
                for (int i = 0; i < DDIM; i += 4) {
                    float4 x = *reinterpret_cast<const float4*>(wr + i);
                    acc = fmaf(hreg[i + 0], x.x, acc);
                    acc = fmaf(hreg[i + 1], x.y, acc);
                    acc = fmaf(hreg[i + 2], x.z, acc);
                    acc = fmaf(hreg[i + 3], x.w, acc);
                }
                dbest = __fsub_rn(__fadd_rn(Af, bsq[k]), __fadd_rn(acc, acc));
                kbest = k;
            }
        } else {
            // overflow: deterministic exact full scan
            for (int k = lane; k < KCB; k += 64) {
                const float* wr = w + (size_t)k * DDIM;
                float acc = 0.f;
#pragma unroll
                for (int i = 0; i < DDIM; i += 4) {
                    float4 x = *reinterpret_cast<const float4*>(wr + i);
                    acc = fmaf(hreg[i + 0], x.x, acc);
                    acc = fmaf(hreg[i + 1], x.y, acc);
                    acc = fmaf(hreg[i + 2], x.z, acc);
                    acc = fmaf(hreg[i + 3], x.w, acc);
                }
                float d = __fsub_rn(__fadd_rn(Af, bsq[k]), __fadd_rn(acc, acc));
                if (d < dbest || (d == dbest && k < kbest)) { dbest = d; kbest = k; }
            }
        }
        // lexicographic (d, k) min across lanes == np.argmin first-min
#pragma unroll
        for (int off = 1; off < 64; off <<= 1) {
            float od = __shfl_xor(dbest, off);
            int ok = __shfl_xor(kbest, off);
            bool take = (od < dbest) || (od == dbest && ok < kbest);
            dbest = take ? od : dbest;
            kbest = take ? ok : kbest;
        }
        if (lane == 0) out[NQ + n_glob] = (float)kbest;
    }
}

// ---------- K4: frozen epilogue (qst + loss); idx already written by K3 ----------
__global__ __launch_bounds__(256)
void vq_epilogue(const float* __restrict__ h, const float* __restrict__ w,
                 float* __restrict__ out) {
    const size_t n = (size_t)blockIdx.x * 256 + threadIdx.x;
    const int bk = (int)out[NQ + n];
    const float* hrow = h + n * DDIM;
    float hr[DDIM];
#pragma unroll
    for (int i = 0; i < DDIM; i += 4) {
        float4 v = *reinterpret_cast<const float4*>(hrow + i);
        hr[i] = v.x; hr[i + 1] = v.y; hr[i + 2] = v.z; hr[i + 3] = v.w;
    }
    const float* qrow = w + (size_t)bk * DDIM;
    float* qst = out + n * DDIM;
    float r2[8];
#pragma unroll
    for (int c = 0; c < 8; ++c) {
        float4 qa = *reinterpret_cast<const float4*>(qrow + 8 * c);
        float4 qb = *reinterpret_cast<const float4*>(qrow + 8 * c + 4);
        float d0 = __fsub_rn(qa.x, hr[8 * c + 0]);
        float d1 = __fsub_rn(qa.y, hr[8 * c + 1]);
        float d2 = __fsub_rn(qa.z, hr[8 * c + 2]);
        float d3 = __fsub_rn(qa.w, hr[8 * c + 3]);
        float d4 = __fsub_rn(qb.x, hr[8 * c + 4]);
        float d5 = __fsub_rn(qb.y, hr[8 * c + 5]);
        float d6 = __fsub_rn(qb.z, hr[8 * c + 6]);
        float d7 = __fsub_rn(qb.w, hr[8 * c + 7]);
        if (c == 0) {
            r2[0] = __fmul_rn(d0, d0); r2[1] = __fmul_rn(d1, d1);
            r2[2] = __fmul_rn(d2, d2); r2[3] = __fmul_rn(d3, d3);
            r2[4] = __fmul_rn(d4, d4); r2[5] = __fmul_rn(d5, d5);
            r2[6] = __fmul_rn(d6, d6); r2[7] = __fmul_rn(d7, d7);
        } else {
            r2[0] = __fadd_rn(r2[0], __fmul_rn(d0, d0));
            r2[1] = __fadd_rn(r2[1], __fmul_rn(d1, d1));
            r2[2] = __fadd_rn(r2[2], __fmul_rn(d2, d2));
            r2[3] = __fadd_rn(r2[3], __fmul_rn(d3, d3));
            r2[4] = __fadd_rn(r2[4], __fmul_rn(d4, d4));
            r2[5] = __fadd_rn(r2[5], __fmul_rn(d5, d5));
            r2[6] = __fadd_rn(r2[6], __fmul_rn(d6, d6));
            r2[7] = __fadd_rn(r2[7], __fmul_rn(d7, d7));
        }
        float4 oa, ob;
        oa.x = __fadd_rn(hr[8 * c + 0], d0);
        oa.y = __fadd_rn(hr[8 * c + 1], d1);
        oa.z = __fadd_rn(hr[8 * c + 2], d2);
        oa.w = __fadd_rn(hr[8 * c + 3], d3);
        ob.x = __fadd_rn(hr[8 * c + 4], d4);
        ob.y = __fadd_rn(hr[8 * c + 5], d5);
        ob.z = __fadd_rn(hr[8 * c + 6], d6);
        ob.w = __fadd_rn(hr[8 * c + 7], d7);
        *reinterpret_cast<float4*>(qst + 8 * c) = oa;
        *reinterpret_cast<float4*>(qst + 8 * c + 4) = ob;
    }
    float S = __fadd_rn(__fadd_rn(__fadd_rn(r2[0], r2[1]), __fadd_rn(r2[2], r2[3])),
                        __fadd_rn(__fadd_rn(r2[4], r2[5]), __fadd_rn(r2[6], r2[7])));
    float m = __fmul_rn(S, 0.015625f);
    out[NQ + NROWS + n] = __fadd_rn(__fmul_rn(m, 0.1f), __fmul_rn(m, 0.2f));
}

extern "C" void kernel_launch(void* const* d_in, const int* in_sizes, int n_in,
                              void* d_out, int out_size, void* d_ws, size_t ws_size,
                              hipStream_t stream) {
    (void)in_sizes; (void)n_in; (void)out_size; (void)ws_size;
    const float* h = (const float*)d_in[0];
    const float* w = (const float*)d_in[1];
    float* out = (float*)d_out;

    // d_ws layout (≈1.14 MB): bsq 4KB | wmax 16B pad→8KB | wbf 128KB | asq 1MB
    char* ws = (char*)d_ws;
    float* bsq = (float*)ws;
    float* wmaxp = (float*)(ws + 4096);
    unsigned short* wbf = (unsigned short*)(ws + 8192);
    float* asq = (float*)(ws + 8192 + KCB * DDIM * sizeof(unsigned short));

    prep_w<<<1, 1024, 0, stream>>>(w, bsq, wbf, wmaxp);
    prep_h<<<NROWS / 256, 256, 0, stream>>>(h, asq);
    vq_scan<<<NROWS / RPB, 256, 0, stream>>>(h, w, wbf, bsq, asq, wmaxp, out);
    vq_epilogue<<<NROWS / 256, 256, 0, stream>>>(h, w, out);
}

// Round 11
// 398.503 us; speedup vs baseline: 1.3955x; 1.3065x over previous
//
#include <hip/hip_runtime.h>
#include <math.h>

#define NROWS (512 * 512)
#define KCB   1024
#define DDIM  64
#define NQ    ((size_t)NROWS * DDIM)
#define RPB   32            // h-rows per block in scan kernel
#define CMAX  64            // candidate cap per row

typedef __attribute__((ext_vector_type(8))) short bf16x8;
typedef __attribute__((ext_vector_type(4))) float f32x4;

__device__ __forceinline__ unsigned short f2bf(float x) {
    unsigned u = __float_as_uint(x);
    u = u + 0x7FFFu + ((u >> 16) & 1u);
    return (unsigned short)(u >> 16);
}
__device__ __forceinline__ unsigned fsort(float d) {   // monotonic f32 -> u32
    unsigned u = __float_as_uint(d);
    return (u & 0x80000000u) ? ~u : (u | 0x80000000u);
}

// ---------- K1: frozen wsq + w->bf16 + wmax ----------
__global__ __launch_bounds__(1024)
void prep_w(const float* __restrict__ w, float* __restrict__ bsq,
            unsigned short* __restrict__ wbf, float* __restrict__ wmaxp) {
    __shared__ float red[16];
    const int k = threadIdx.x;
    const float* row = w + (size_t)k * DDIM;
    float r[8];
#pragma unroll
    for (int j = 0; j < 8; ++j) r[j] = __fmul_rn(row[j], row[j]);
#pragma unroll
    for (int i = 8; i < DDIM; i += 8)
#pragma unroll
        for (int j = 0; j < 8; ++j)
            r[j] = __fadd_rn(r[j], __fmul_rn(row[i + j], row[i + j]));
    float b = __fadd_rn(__fadd_rn(__fadd_rn(r[0], r[1]), __fadd_rn(r[2], r[3])),
                        __fadd_rn(__fadd_rn(r[4], r[5]), __fadd_rn(r[6], r[7])));
    bsq[k] = b;
    unsigned* dst = (unsigned*)(wbf + (size_t)k * DDIM);
#pragma unroll
    for (int j = 0; j < 32; ++j)
        dst[j] = (unsigned)f2bf(row[2 * j]) | ((unsigned)f2bf(row[2 * j + 1]) << 16);
    float v = sqrtf(b) * 1.02f;
#pragma unroll
    for (int off = 1; off < 64; off <<= 1) v = fmaxf(v, __shfl_xor(v, off));
    if ((threadIdx.x & 63) == 0) red[threadIdx.x >> 6] = v;
    __syncthreads();
    if (threadIdx.x == 0) {
        float m = red[0];
#pragma unroll
        for (int j = 1; j < 16; ++j) m = fmaxf(m, red[j]);
        *wmaxp = m;
    }
}

// ---------- K2: frozen asq (numpy pairwise-8) ----------
__global__ __launch_bounds__(256)
void prep_h(const float* __restrict__ h, float* __restrict__ asq) {
    const size_t n = (size_t)blockIdx.x * 256 + threadIdx.x;
    const float* row = h + n * DDIM;
    float hr[DDIM];
#pragma unroll
    for (int i = 0; i < DDIM; i += 4) {
        float4 v = *reinterpret_cast<const float4*>(row + i);
        hr[i] = v.x; hr[i + 1] = v.y; hr[i + 2] = v.z; hr[i + 3] = v.w;
    }
    float s[8];
#pragma unroll
    for (int j = 0; j < 8; ++j) s[j] = __fmul_rn(hr[j], hr[j]);
#pragma unroll
    for (int i = 8; i < DDIM; i += 8)
#pragma unroll
        for (int j = 0; j < 8; ++j)
            s[j] = __fadd_rn(s[j], __fmul_rn(hr[i + j], hr[i + j]));
    asq[n] = __fadd_rn(__fadd_rn(__fadd_rn(s[0], s[1]), __fadd_rn(s[2], s[3])),
                       __fadd_rn(__fadd_rn(s[4], s[5]), __fadd_rn(s[6], s[7])));
}

// ---------- K3: two-pass MFMA scan, register mins, atomicMin-key rescore ----------
__global__ __launch_bounds__(256, 2)
void vq_scan(const float* __restrict__ h, const float* __restrict__ w,
             const unsigned short* __restrict__ wbf, const float* __restrict__ bsq,
             const float* __restrict__ asq, const float* __restrict__ wmaxp,
             float* __restrict__ out) {
    __shared__ float smin[4][RPB];
    __shared__ float sthr[RPB];
    __shared__ int scnt[RPB];
    __shared__ int sclist[RPB][CMAX];
    __shared__ unsigned long long sbkey[RPB];

    const int tid = threadIdx.x;
    const int wv = tid >> 6, lane = tid & 63;
    const int l16 = lane & 15, lh = lane >> 4;
    const int rowbase = blockIdx.x * RPB;

    if (tid < RPB) { scnt[tid] = 0; sbkey[tid] = 0xFFFFFFFFFFFFFFFFULL; }

    // A-frags (h rows, bf16) — layout validated R10
    bf16x8 afr[2][2];
#pragma unroll
    for (int mt = 0; mt < 2; ++mt) {
        const float* hrow = h + ((size_t)(rowbase + mt * 16 + l16)) * DDIM;
#pragma unroll
        for (int dh = 0; dh < 2; ++dh) {
            float4 a = *reinterpret_cast<const float4*>(hrow + dh * 32 + lh * 8);
            float4 bq = *reinterpret_cast<const float4*>(hrow + dh * 32 + lh * 8 + 4);
            union { bf16x8 v; unsigned short u[8]; } pk;
            pk.u[0] = f2bf(a.x); pk.u[1] = f2bf(a.y); pk.u[2] = f2bf(a.z); pk.u[3] = f2bf(a.w);
            pk.u[4] = f2bf(bq.x); pk.u[5] = f2bf(bq.y); pk.u[6] = f2bf(bq.z); pk.u[7] = f2bf(bq.w);
            afr[mt][dh] = pk.v;
        }
    }

    // ---- pass A: per-lane running mins of its 8 fixed C-rows ----
    float pmin[8];
#pragma unroll
    for (int j = 0; j < 8; ++j) pmin[j] = INFINITY;
#pragma unroll 2
    for (int nt = wv; nt < KCB / 16; nt += 4) {
        const unsigned short* wrow = wbf + (size_t)(nt * 16 + l16) * DDIM;
        bf16x8 bfr0 = *reinterpret_cast<const bf16x8*>(wrow + lh * 8);
        bf16x8 bfr1 = *reinterpret_cast<const bf16x8*>(wrow + 32 + lh * 8);
        float bq = bsq[nt * 16 + l16];
#pragma unroll
        for (int mt = 0; mt < 2; ++mt) {
            f32x4 acc = {0.f, 0.f, 0.f, 0.f};
            acc = __builtin_amdgcn_mfma_f32_16x16x32_bf16(afr[mt][0], bfr0, acc, 0, 0, 0);
            acc = __builtin_amdgcn_mfma_f32_16x16x32_bf16(afr[mt][1], bfr1, acc, 0, 0, 0);
#pragma unroll
            for (int i = 0; i < 4; ++i) {
                float val = bq - (acc[i] + acc[i]);
                pmin[mt * 4 + i] = fminf(pmin[mt * 4 + i], val);
            }
        }
    }
    // reduce over the 16 l16-lanes (same C-rows), offsets 1,2,4,8 only
#pragma unroll
    for (int off = 1; off < 16; off <<= 1)
#pragma unroll
        for (int j = 0; j < 8; ++j) pmin[j] = fminf(pmin[j], __shfl_xor(pmin[j], off));
    if (l16 == 0) {
#pragma unroll
        for (int mt = 0; mt < 2; ++mt)
#pragma unroll
            for (int i = 0; i < 4; ++i)
                smin[wv][mt * 16 + lh * 4 + i] = pmin[mt * 4 + i];
    }
    __syncthreads();
    if (tid < RPB) {
        float m = fminf(fminf(smin[0][tid], smin[1][tid]), fminf(smin[2][tid], smin[3][tid]));
        float Af = asq[rowbase + tid];
        sthr[tid] = m + sqrtf(Af) * 1.001f * (*wmaxp) * 0.03125f + 1e-3f;  // 4x analytic + slack
    }
    __syncthreads();

    // per-lane thresholds for its 8 fixed rows
    float tr[8];
#pragma unroll
    for (int mt = 0; mt < 2; ++mt)
#pragma unroll
        for (int i = 0; i < 4; ++i) tr[mt * 4 + i] = sthr[mt * 16 + lh * 4 + i];

    // ---- pass B: recompute, collect candidates ----
#pragma unroll 2
    for (int nt = wv; nt < KCB / 16; nt += 4) {
        const unsigned short* wrow = wbf + (size_t)(nt * 16 + l16) * DDIM;
        bf16x8 bfr0 = *reinterpret_cast<const bf16x8*>(wrow + lh * 8);
        bf16x8 bfr1 = *reinterpret_cast<const bf16x8*>(wrow + 32 + lh * 8);
        float bq = bsq[nt * 16 + l16];
#pragma unroll
        for (int mt = 0; mt < 2; ++mt) {
            f32x4 acc = {0.f, 0.f, 0.f, 0.f};
            acc = __builtin_amdgcn_mfma_f32_16x16x32_bf16(afr[mt][0], bfr0, acc, 0, 0, 0);
            acc = __builtin_amdgcn_mfma_f32_16x16x32_bf16(afr[mt][1], bfr1, acc, 0, 0, 0);
#pragma unroll
            for (int i = 0; i < 4; ++i) {
                float val = bq - (acc[i] + acc[i]);
                if (val <= tr[mt * 4 + i]) {
                    int row = mt * 16 + lh * 4 + i;
                    int slot = atomicAdd(&scnt[row], 1);
                    if (slot < CMAX) sclist[row][slot] = nt * 16 + l16;
                }
            }
        }
    }
    __syncthreads();

    // ---- rescore: 8 threads per row, exact frozen chain, atomicMin key ----
    {
        const int row = tid >> 3;
        const int s0 = tid & 7;
        const int cnt = scnt[row];
        const size_t ng = (size_t)rowbase + row;
        if (cnt <= CMAX && s0 < cnt) {
            const float Af = asq[ng];
            const float* hrow = h + ng * DDIM;
            float hreg[DDIM];
#pragma unroll
            for (int i = 0; i < DDIM; i += 4) {
                float4 v = *reinterpret_cast<const float4*>(hrow + i);
                hreg[i] = v.x; hreg[i + 1] = v.y; hreg[i + 2] = v.z; hreg[i + 3] = v.w;
            }
            for (int slot = s0; slot < cnt; slot += 8) {
                int k = sclist[row][slot];
                const float* wr = w + (size_t)k * DDIM;
                float acc = 0.f;
#pragma unroll
                for (int i = 0; i < DDIM; i += 4) {
                    float4 x = *reinterpret_cast<const float4*>(wr + i);
                    acc = fmaf(hreg[i + 0], x.x, acc);
                    acc = fmaf(hreg[i + 1], x.y, acc);
                    acc = fmaf(hreg[i + 2], x.z, acc);
                    acc = fmaf(hreg[i + 3], x.w, acc);
                }
                float d = __fsub_rn(__fadd_rn(Af, bsq[k]), __fadd_rn(acc, acc));
                unsigned long long key = ((unsigned long long)fsort(d) << 32) | (unsigned)k;
                atomicMin(&sbkey[row], key);
            }
        }
    }
    // overflow fallback (deterministic full scan; effectively never taken)
#pragma unroll 1
    for (int r = 0; r < RPB; ++r) {
        if (scnt[r] > CMAX) {
            const size_t ng = (size_t)rowbase + r;
            const float Af = asq[ng];
            const float* hrow = h + ng * DDIM;
            float hreg[DDIM];
#pragma unroll
            for (int i = 0; i < DDIM; i += 4) {
                float4 v = *reinterpret_cast<const float4*>(hrow + i);
                hreg[i] = v.x; hreg[i + 1] = v.y; hreg[i + 2] = v.z; hreg[i + 3] = v.w;
            }
            for (int k = tid; k < KCB; k += 256) {
                const float* wr = w + (size_t)k * DDIM;
                float acc = 0.f;
#pragma unroll
                for (int i = 0; i < DDIM; i += 4) {
                    float4 x = *reinterpret_cast<const float4*>(wr + i);
                    acc = fmaf(hreg[i + 0], x.x, acc);
                    acc = fmaf(hreg[i + 1], x.y, acc);
                    acc = fmaf(hreg[i + 2], x.z, acc);
                    acc = fmaf(hreg[i + 3], x.w, acc);
                }
                float d = __fsub_rn(__fadd_rn(Af, bsq[k]), __fadd_rn(acc, acc));
                unsigned long long key = ((unsigned long long)fsort(d) << 32) | (unsigned)k;
                atomicMin(&sbkey[r], key);
            }
        }
    }
    __syncthreads();
    if (tid < RPB)
        out[NQ + rowbase + tid] = (float)(unsigned)(sbkey[tid] & 0xFFFFFFFFu);
}

// ---------- K4: frozen epilogue (qst + loss) ----------
__global__ __launch_bounds__(256)
void vq_epilogue(const float* __restrict__ h, const float* __restrict__ w,
                 float* __restrict__ out) {
    const size_t n = (size_t)blockIdx.x * 256 + threadIdx.x;
    const int bk = (int)out[NQ + n];
    const float* hrow = h + n * DDIM;
    float hr[DDIM];
#pragma unroll
    for (int i = 0; i < DDIM; i += 4) {
        float4 v = *reinterpret_cast<const float4*>(hrow + i);
        hr[i] = v.x; hr[i + 1] = v.y; hr[i + 2] = v.z; hr[i + 3] = v.w;
    }
    const float* qrow = w + (size_t)bk * DDIM;
    float* qst = out + n * DDIM;
    float r2[8];
#pragma unroll
    for (int c = 0; c < 8; ++c) {
        float4 qa = *reinterpret_cast<const float4*>(qrow + 8 * c);
        float4 qb = *reinterpret_cast<const float4*>(qrow + 8 * c + 4);
        float d0 = __fsub_rn(qa.x, hr[8 * c + 0]);
        float d1 = __fsub_rn(qa.y, hr[8 * c + 1]);
        float d2 = __fsub_rn(qa.z, hr[8 * c + 2]);
        float d3 = __fsub_rn(qa.w, hr[8 * c + 3]);
        float d4 = __fsub_rn(qb.x, hr[8 * c + 4]);
        float d5 = __fsub_rn(qb.y, hr[8 * c + 5]);
        float d6 = __fsub_rn(qb.z, hr[8 * c + 6]);
        float d7 = __fsub_rn(qb.w, hr[8 * c + 7]);
        if (c == 0) {
            r2[0] = __fmul_rn(d0, d0); r2[1] = __fmul_rn(d1, d1);
            r2[2] = __fmul_rn(d2, d2); r2[3] = __fmul_rn(d3, d3);
            r2[4] = __fmul_rn(d4, d4); r2[5] = __fmul_rn(d5, d5);
            r2[6] = __fmul_rn(d6, d6); r2[7] = __fmul_rn(d7, d7);
        } else {
            r2[0] = __fadd_rn(r2[0], __fmul_rn(d0, d0));
            r2[1] = __fadd_rn(r2[1], __fmul_rn(d1, d1));
            r2[2] = __fadd_rn(r2[2], __fmul_rn(d2, d2));
            r2[3] = __fadd_rn(r2[3], __fmul_rn(d3, d3));
            r2[4] = __fadd_rn(r2[4], __fmul_rn(d4, d4));
            r2[5] = __fadd_rn(r2[5], __fmul_rn(d5, d5));
            r2[6] = __fadd_rn(r2[6], __fmul_rn(d6, d6));
            r2[7] = __fadd_rn(r2[7], __fmul_rn(d7, d7));
        }
        float4 oa, ob;
        oa.x = __fadd_rn(hr[8 * c + 0], d0);
        oa.y = __fadd_rn(hr[8 * c + 1], d1);
        oa.z = __fadd_rn(hr[8 * c + 2], d2);
        oa.w = __fadd_rn(hr[8 * c + 3], d3);
        ob.x = __fadd_rn(hr[8 * c + 4], d4);
        ob.y = __fadd_rn(hr[8 * c + 5], d5);
        ob.z = __fadd_rn(hr[8 * c + 6], d6);
        ob.w = __fadd_rn(hr[8 * c + 7], d7);
        *reinterpret_cast<float4*>(qst + 8 * c) = oa;
        *reinterpret_cast<float4*>(qst + 8 * c + 4) = ob;
    }
    float S = __fadd_rn(__fadd_rn(__fadd_rn(r2[0], r2[1]), __fadd_rn(r2[2], r2[3])),
                        __fadd_rn(__fadd_rn(r2[4], r2[5]), __fadd_rn(r2[6], r2[7])));
    float m = __fmul_rn(S, 0.015625f);
    out[NQ + NROWS + n] = __fadd_rn(__fmul_rn(m, 0.1f), __fmul_rn(m, 0.2f));
}

extern "C" void kernel_launch(void* const* d_in, const int* in_sizes, int n_in,
                              void* d_out, int out_size, void* d_ws, size_t ws_size,
                              hipStream_t stream) {
    (void)in_sizes; (void)n_in; (void)out_size; (void)ws_size;
    const float* h = (const float*)d_in[0];
    const float* w = (const float*)d_in[1];
    float* out = (float*)d_out;

    char* ws = (char*)d_ws;
    float* bsq = (float*)ws;                               // 4 KB
    float* wmaxp = (float*)(ws + 4096);                    // 16 B
    unsigned short* wbf = (unsigned short*)(ws + 8192);    // 128 KB
    float* asq = (float*)(ws + 8192 + KCB * DDIM * sizeof(unsigned short));  // 1 MB

    prep_w<<<1, 1024, 0, stream>>>(w, bsq, wbf, wmaxp);
    prep_h<<<NROWS / 256, 256, 0, stream>>>(h, asq);
    vq_scan<<<NROWS / RPB, 256, 0, stream>>>(h, w, wbf, bsq, asq, wmaxp, out);
    vq_epilogue<<<NROWS / 256, 256, 0, stream>>>(h, w, out);
}

// Round 12
// 395.307 us; speedup vs baseline: 1.4068x; 1.0081x over previous
//
#include <hip/hip_runtime.h>
#include <math.h>

#define NROWS (512 * 512)
#define KCB   1024
#define DDIM  64
#define NQ    ((size_t)NROWS * DDIM)
#define RPB   32            // h-rows per block
#define CMAX  64            // candidate cap per row
#define WAVES 8
#define BLKT  512
#define NTW   (KCB / 16 / WAVES)   // 8 nt tiles per wave

typedef __attribute__((ext_vector_type(8))) short bf16x8;
typedef __attribute__((ext_vector_type(4))) float f32x4;

__device__ __forceinline__ unsigned short f2bf(float x) {
    unsigned u = __float_as_uint(x);
    u = u + 0x7FFFu + ((u >> 16) & 1u);
    return (unsigned short)(u >> 16);
}
__device__ __forceinline__ float bfhi2f(unsigned u) { return __uint_as_float(u & 0xFFFF0000u); }
__device__ __forceinline__ float bflo2f(unsigned u) { return __uint_as_float(u << 16); }
__device__ __forceinline__ unsigned fsort(float d) {   // monotonic f32 -> u32
    unsigned u = __float_as_uint(d);
    return (u & 0x80000000u) ? ~u : (u | 0x80000000u);
}

// ---------- K1: frozen wsq + w->bf16 + wmax ----------
__global__ __launch_bounds__(1024)
void prep_w(const float* __restrict__ w, float* __restrict__ bsq,
            unsigned short* __restrict__ wbf, float* __restrict__ wmaxp) {
    __shared__ float red[16];
    const int k = threadIdx.x;
    const float* row = w + (size_t)k * DDIM;
    float r[8];
#pragma unroll
    for (int j = 0; j < 8; ++j) r[j] = __fmul_rn(row[j], row[j]);
#pragma unroll
    for (int i = 8; i < DDIM; i += 8)
#pragma unroll
        for (int j = 0; j < 8; ++j)
            r[j] = __fadd_rn(r[j], __fmul_rn(row[i + j], row[i + j]));
    float b = __fadd_rn(__fadd_rn(__fadd_rn(r[0], r[1]), __fadd_rn(r[2], r[3])),
                        __fadd_rn(__fadd_rn(r[4], r[5]), __fadd_rn(r[6], r[7])));
    bsq[k] = b;
    unsigned* dst = (unsigned*)(wbf + (size_t)k * DDIM);
#pragma unroll
    for (int j = 0; j < 32; ++j)
        dst[j] = (unsigned)f2bf(row[2 * j]) | ((unsigned)f2bf(row[2 * j + 1]) << 16);
    float v = sqrtf(b) * 1.02f;
#pragma unroll
    for (int off = 1; off < 64; off <<= 1) v = fmaxf(v, __shfl_xor(v, off));
    if ((threadIdx.x & 63) == 0) red[threadIdx.x >> 6] = v;
    __syncthreads();
    if (threadIdx.x == 0) {
        float m = red[0];
#pragma unroll
        for (int j = 1; j < 16; ++j) m = fmaxf(m, red[j]);
        *wmaxp = m;
    }
}

// ---------- K3: single-pass MFMA scan w/ register val-cache + fused Af ----------
__global__ __launch_bounds__(BLKT, 4)
void vq_scan(const float* __restrict__ h, const float* __restrict__ w,
             const unsigned short* __restrict__ wbf, const float* __restrict__ bsq,
             const float* __restrict__ wmaxp, float* __restrict__ out) {
    __shared__ float smin[WAVES][RPB];
    __shared__ float sthr[RPB];
    __shared__ float sAf[RPB];
    __shared__ int scnt[RPB];
    __shared__ int sclist[RPB][CMAX];
    __shared__ unsigned long long sbkey[RPB];

    const int tid = threadIdx.x;
    const int wv = tid >> 6, lane = tid & 63;
    const int l16 = lane & 15, lh = lane >> 4;
    const int rowbase = blockIdx.x * RPB;

    if (tid < RPB) { scnt[tid] = 0; sbkey[tid] = 0xFFFFFFFFFFFFFFFFULL; }

    // fused prep_h: frozen pairwise-8 Af for the block's 32 rows (threads 0..31)
    if (tid < RPB) {
        const float* row = h + (size_t)(rowbase + tid) * DDIM;
        float hr[DDIM];
#pragma unroll
        for (int i = 0; i < DDIM; i += 4) {
            float4 v = *reinterpret_cast<const float4*>(row + i);
            hr[i] = v.x; hr[i + 1] = v.y; hr[i + 2] = v.z; hr[i + 3] = v.w;
        }
        float s[8];
#pragma unroll
        for (int j = 0; j < 8; ++j) s[j] = __fmul_rn(hr[j], hr[j]);
#pragma unroll
        for (int i = 8; i < DDIM; i += 8)
#pragma unroll
            for (int j = 0; j < 8; ++j)
                s[j] = __fadd_rn(s[j], __fmul_rn(hr[i + j], hr[i + j]));
        sAf[tid] = __fadd_rn(__fadd_rn(__fadd_rn(s[0], s[1]), __fadd_rn(s[2], s[3])),
                             __fadd_rn(__fadd_rn(s[4], s[5]), __fadd_rn(s[6], s[7])));
    }

    // A-frags (h rows, bf16) — layout validated R10/R11
    bf16x8 afr[2][2];
#pragma unroll
    for (int mt = 0; mt < 2; ++mt) {
        const float* hrow = h + ((size_t)(rowbase + mt * 16 + l16)) * DDIM;
#pragma unroll
        for (int dh = 0; dh < 2; ++dh) {
            float4 a = *reinterpret_cast<const float4*>(hrow + dh * 32 + lh * 8);
            float4 bq = *reinterpret_cast<const float4*>(hrow + dh * 32 + lh * 8 + 4);
            union { bf16x8 v; unsigned short u[8]; } pk;
            pk.u[0] = f2bf(a.x); pk.u[1] = f2bf(a.y); pk.u[2] = f2bf(a.z); pk.u[3] = f2bf(a.w);
            pk.u[4] = f2bf(bq.x); pk.u[5] = f2bf(bq.y); pk.u[6] = f2bf(bq.z); pk.u[7] = f2bf(bq.w);
            afr[mt][dh] = pk.v;
        }
    }

    // ---- pass A (single pass): MFMA, running mins, bf16-packed register val cache ----
    float pmin[8];
#pragma unroll
    for (int j = 0; j < 8; ++j) pmin[j] = INFINITY;
    unsigned vals[NTW][2][2];     // static-indexed via full unroll (stays in VGPRs)

#pragma unroll
    for (int no = 0; no < NTW; ++no) {
        const int nt = no * WAVES + wv;
        const unsigned short* wrow = wbf + (size_t)(nt * 16 + l16) * DDIM;
        bf16x8 bfr0 = *reinterpret_cast<const bf16x8*>(wrow + lh * 8);
        bf16x8 bfr1 = *reinterpret_cast<const bf16x8*>(wrow + 32 + lh * 8);
        float bq = bsq[nt * 16 + l16];
#pragma unroll
        for (int mt = 0; mt < 2; ++mt) {
            f32x4 acc = {0.f, 0.f, 0.f, 0.f};
            acc = __builtin_amdgcn_mfma_f32_16x16x32_bf16(afr[mt][0], bfr0, acc, 0, 0, 0);
            acc = __builtin_amdgcn_mfma_f32_16x16x32_bf16(afr[mt][1], bfr1, acc, 0, 0, 0);
            float v0 = bq - (acc[0] + acc[0]);
            float v1 = bq - (acc[1] + acc[1]);
            float v2 = bq - (acc[2] + acc[2]);
            float v3 = bq - (acc[3] + acc[3]);
            pmin[mt * 4 + 0] = fminf(pmin[mt * 4 + 0], v0);
            pmin[mt * 4 + 1] = fminf(pmin[mt * 4 + 1], v1);
            pmin[mt * 4 + 2] = fminf(pmin[mt * 4 + 2], v2);
            pmin[mt * 4 + 3] = fminf(pmin[mt * 4 + 3], v3);
            vals[no][mt][0] = (unsigned)f2bf(v0) | ((unsigned)f2bf(v1) << 16);
            vals[no][mt][1] = (unsigned)f2bf(v2) | ((unsigned)f2bf(v3) << 16);
        }
    }

    // reduce mins over the 16 l16-lanes (same C-rows)
#pragma unroll
    for (int off = 1; off < 16; off <<= 1)
#pragma unroll
        for (int j = 0; j < 8; ++j) pmin[j] = fminf(pmin[j], __shfl_xor(pmin[j], off));
    if (l16 == 0) {
#pragma unroll
        for (int mt = 0; mt < 2; ++mt)
#pragma unroll
            for (int i = 0; i < 4; ++i)
                smin[wv][mt * 16 + lh * 4 + i] = pmin[mt * 4 + i];
    }
    __syncthreads();

    if (tid < RPB) {
        float m = smin[0][tid];
#pragma unroll
        for (int q = 1; q < WAVES; ++q) m = fminf(m, smin[q][tid]);
        sthr[tid] = m + sqrtf(sAf[tid]) * 1.001f * (*wmaxp) * 0.03125f + 1e-3f;  // validated margin
    }
    __syncthreads();

    float tr[8];
#pragma unroll
    for (int mt = 0; mt < 2; ++mt)
#pragma unroll
        for (int i = 0; i < 4; ++i) tr[mt * 4 + i] = sthr[mt * 16 + lh * 4 + i];

    // ---- candidate scan from registers (no MFMA recompute, no loads) ----
#pragma unroll
    for (int no = 0; no < NTW; ++no) {
        const int kk = (no * WAVES + wv) * 16 + l16;
#pragma unroll
        for (int mt = 0; mt < 2; ++mt) {
#pragma unroll
            for (int p = 0; p < 2; ++p) {
                unsigned u = vals[no][mt][p];
                float vlo = bflo2f(u), vhi = bfhi2f(u);
                if (vlo <= tr[mt * 4 + 2 * p]) {
                    int row = mt * 16 + lh * 4 + 2 * p;
                    int slot = atomicAdd(&scnt[row], 1);
                    if (slot < CMAX) sclist[row][slot] = kk;
                }
                if (vhi <= tr[mt * 4 + 2 * p + 1]) {
                    int row = mt * 16 + lh * 4 + 2 * p + 1;
                    int slot = atomicAdd(&scnt[row], 1);
                    if (slot < CMAX) sclist[row][slot] = kk;
                }
            }
        }
    }
    __syncthreads();

    // ---- rescore: 16 threads/row, exact frozen chain, atomicMin key ----
    {
        const int row = tid >> 4;
        const int s0 = tid & 15;
        const int cnt = scnt[row];
        if (cnt <= CMAX && s0 < cnt) {
            const size_t ng = (size_t)rowbase + row;
            const float Af = sAf[row];
            const float* hrow = h + ng * DDIM;
            float hreg[DDIM];
#pragma unroll
            for (int i = 0; i < DDIM; i += 4) {
                float4 v = *reinterpret_cast<const float4*>(hrow + i);
                hreg[i] = v.x; hreg[i + 1] = v.y; hreg[i + 2] = v.z; hreg[i + 3] = v.w;
            }
            for (int slot = s0; slot < cnt; slot += 16) {
                int k = sclist[row][slot];
                const float* wr = w + (size_t)k * DDIM;
                float acc = 0.f;
#pragma unroll
                for (int i = 0; i < DDIM; i += 4) {
                    float4 x = *reinterpret_cast<const float4*>(wr + i);
                    acc = fmaf(hreg[i + 0], x.x, acc);
                    acc = fmaf(hreg[i + 1], x.y, acc);
                    acc = fmaf(hreg[i + 2], x.z, acc);
                    acc = fmaf(hreg[i + 3], x.w, acc);
                }
                float d = __fsub_rn(__fadd_rn(Af, bsq[k]), __fadd_rn(acc, acc));
                unsigned long long key = ((unsigned long long)fsort(d) << 32) | (unsigned)k;
                atomicMin(&sbkey[row], key);
            }
        }
    }
    // overflow fallback (deterministic full scan; effectively never taken)
#pragma unroll 1
    for (int r = 0; r < RPB; ++r) {
        if (scnt[r] > CMAX) {
            const size_t ng = (size_t)rowbase + r;
            const float Af = sAf[r];
            const float* hrow = h + ng * DDIM;
            float hreg[DDIM];
#pragma unroll
            for (int i = 0; i < DDIM; i += 4) {
                float4 v = *reinterpret_cast<const float4*>(hrow + i);
                hreg[i] = v.x; hreg[i + 1] = v.y; hreg[i + 2] = v.z; hreg[i + 3] = v.w;
            }
            for (int k = tid; k < KCB; k += BLKT) {
                const float* wr = w + (size_t)k * DDIM;
                float acc = 0.f;
#pragma unroll
                for (int i = 0; i < DDIM; i += 4) {
                    float4 x = *reinterpret_cast<const float4*>(wr + i);
                    acc = fmaf(hreg[i + 0], x.x, acc);
                    acc = fmaf(hreg[i + 1], x.y, acc);
                    acc = fmaf(hreg[i + 2], x.z, acc);
                    acc = fmaf(hreg[i + 3], x.w, acc);
                }
                float d = __fsub_rn(__fadd_rn(Af, bsq[k]), __fadd_rn(acc, acc));
                unsigned long long key = ((unsigned long long)fsort(d) << 32) | (unsigned)k;
                atomicMin(&sbkey[r], key);
            }
        }
    }
    __syncthreads();
    if (tid < RPB)
        out[NQ + rowbase + tid] = (float)(unsigned)(sbkey[tid] & 0xFFFFFFFFu);
}

// ---------- K4: frozen epilogue (qst + loss) ----------
__global__ __launch_bounds__(256)
void vq_epilogue(const float* __restrict__ h, const float* __restrict__ w,
                 float* __restrict__ out) {
    const size_t n = (size_t)blockIdx.x * 256 + threadIdx.x;
    const int bk = (int)out[NQ + n];
    const float* hrow = h + n * DDIM;
    float hr[DDIM];
#pragma unroll
    for (int i = 0; i < DDIM; i += 4) {
        float4 v = *reinterpret_cast<const float4*>(hrow + i);
        hr[i] = v.x; hr[i + 1] = v.y; hr[i + 2] = v.z; hr[i + 3] = v.w;
    }
    const float* qrow = w + (size_t)bk * DDIM;
    float* qst = out + n * DDIM;
    float r2[8];
#pragma unroll
    for (int c = 0; c < 8; ++c) {
        float4 qa = *reinterpret_cast<const float4*>(qrow + 8 * c);
        float4 qb = *reinterpret_cast<const float4*>(qrow + 8 * c + 4);
        float d0 = __fsub_rn(qa.x, hr[8 * c + 0]);
        float d1 = __fsub_rn(qa.y, hr[8 * c + 1]);
        float d2 = __fsub_rn(qa.z, hr[8 * c + 2]);
        float d3 = __fsub_rn(qa.w, hr[8 * c + 3]);
        float d4 = __fsub_rn(qb.x, hr[8 * c + 4]);
        float d5 = __fsub_rn(qb.y, hr[8 * c + 5]);
        float d6 = __fsub_rn(qb.z, hr[8 * c + 6]);
        float d7 = __fsub_rn(qb.w, hr[8 * c + 7]);
        if (c == 0) {
            r2[0] = __fmul_rn(d0, d0); r2[1] = __fmul_rn(d1, d1);
            r2[2] = __fmul_rn(d2, d2); r2[3] = __fmul_rn(d3, d3);
            r2[4] = __fmul_rn(d4, d4); r2[5] = __fmul_rn(d5, d5);
            r2[6] = __fmul_rn(d6, d6); r2[7] = __fmul_rn(d7, d7);
        } else {
            r2[0] = __fadd_rn(r2[0], __fmul_rn(d0, d0));
            r2[1] = __fadd_rn(r2[1], __fmul_rn(d1, d1));
            r2[2] = __fadd_rn(r2[2], __fmul_rn(d2, d2));
            r2[3] = __fadd_rn(r2[3], __fmul_rn(d3, d3));
            r2[4] = __fadd_rn(r2[4], __fmul_rn(d4, d4));
            r2[5] = __fadd_rn(r2[5], __fmul_rn(d5, d5));
            r2[6] = __fadd_rn(r2[6], __fmul_rn(d6, d6));
            r2[7] = __fadd_rn(r2[7], __fmul_rn(d7, d7));
        }
        float4 oa, ob;
        oa.x = __fadd_rn(hr[8 * c + 0], d0);
        oa.y = __fadd_rn(hr[8 * c + 1], d1);
        oa.z = __fadd_rn(hr[8 * c + 2], d2);
        oa.w = __fadd_rn(hr[8 * c + 3], d3);
        ob.x = __fadd_rn(hr[8 * c + 4], d4);
        ob.y = __fadd_rn(hr[8 * c + 5], d5);
        ob.z = __fadd_rn(hr[8 * c + 6], d6);
        ob.w = __fadd_rn(hr[8 * c + 7], d7);
        *reinterpret_cast<float4*>(qst + 8 * c) = oa;
        *reinterpret_cast<float4*>(qst + 8 * c + 4) = ob;
    }
    float S = __fadd_rn(__fadd_rn(__fadd_rn(r2[0], r2[1]), __fadd_rn(r2[2], r2[3])),
                        __fadd_rn(__fadd_rn(r2[4], r2[5]), __fadd_rn(r2[6], r2[7])));
    float m = __fmul_rn(S, 0.015625f);
    out[NQ + NROWS + n] = __fadd_rn(__fmul_rn(m, 0.1f), __fmul_rn(m, 0.2f));
}

extern "C" void kernel_launch(void* const* d_in, const int* in_sizes, int n_in,
                              void* d_out, int out_size, void* d_ws, size_t ws_size,
                              hipStream_t stream) {
    (void)in_sizes; (void)n_in; (void)out_size; (void)ws_size;
    const float* h = (const float*)d_in[0];
    const float* w = (const float*)d_in[1];
    float* out = (float*)d_out;

    char* ws = (char*)d_ws;
    float* bsq = (float*)ws;                               // 4 KB
    float* wmaxp = (float*)(ws + 4096);                    // 16 B
    unsigned short* wbf = (unsigned short*)(ws + 8192);    // 128 KB

    prep_w<<<1, 1024, 0, stream>>>(w, bsq, wbf, wmaxp);
    vq_scan<<<NROWS / RPB, BLKT, 0, stream>>>(h, w, wbf, bsq, wmaxp, out);
    vq_epilogue<<<NROWS / 256, 256, 0, stream>>>(h, w, out);
}

// Round 13
// 379.282 us; speedup vs baseline: 1.4663x; 1.0423x over previous
//
#include <hip/hip_runtime.h>
#include <math.h>

#define NROWS (512 * 512)
#define KCB   1024
#define DDIM  64
#define NQ    ((size_t)NROWS * DDIM)
#define RPB   32            // h-rows per block
#define CMAX  64            // candidate cap per row
#define WAVES 8
#define BLKT  512
#define NTW   (KCB / 16 / WAVES)   // 8 nt tiles per wave

typedef __attribute__((ext_vector_type(8))) short bf16x8;
typedef __attribute__((ext_vector_type(4))) float f32x4;

__device__ __forceinline__ unsigned short f2bf(float x) {
    unsigned u = __float_as_uint(x);
    u = u + 0x7FFFu + ((u >> 16) & 1u);
    return (unsigned short)(u >> 16);
}
__device__ __forceinline__ float bfhi2f(unsigned u) { return __uint_as_float(u & 0xFFFF0000u); }
__device__ __forceinline__ float bflo2f(unsigned u) { return __uint_as_float(u << 16); }
__device__ __forceinline__ unsigned fsort(float d) {   // monotonic f32 -> u32
    unsigned u = __float_as_uint(d);
    return (u & 0x80000000u) ? ~u : (u | 0x80000000u);
}

// ---------- K1: frozen wsq + w->bf16 + wmax ----------
__global__ __launch_bounds__(1024)
void prep_w(const float* __restrict__ w, float* __restrict__ bsq,
            unsigned short* __restrict__ wbf, float* __restrict__ wmaxp) {
    __shared__ float red[16];
    const int k = threadIdx.x;
    const float* row = w + (size_t)k * DDIM;
    float r[8];
#pragma unroll
    for (int j = 0; j < 8; ++j) r[j] = __fmul_rn(row[j], row[j]);
#pragma unroll
    for (int i = 8; i < DDIM; i += 8)
#pragma unroll
        for (int j = 0; j < 8; ++j)
            r[j] = __fadd_rn(r[j], __fmul_rn(row[i + j], row[i + j]));
    float b = __fadd_rn(__fadd_rn(__fadd_rn(r[0], r[1]), __fadd_rn(r[2], r[3])),
                        __fadd_rn(__fadd_rn(r[4], r[5]), __fadd_rn(r[6], r[7])));
    bsq[k] = b;
    unsigned* dst = (unsigned*)(wbf + (size_t)k * DDIM);
#pragma unroll
    for (int j = 0; j < 32; ++j)
        dst[j] = (unsigned)f2bf(row[2 * j]) | ((unsigned)f2bf(row[2 * j + 1]) << 16);
    float v = sqrtf(b) * 1.02f;
#pragma unroll
    for (int off = 1; off < 64; off <<= 1) v = fmaxf(v, __shfl_xor(v, off));
    if ((threadIdx.x & 63) == 0) red[threadIdx.x >> 6] = v;
    __syncthreads();
    if (threadIdx.x == 0) {
        float m = red[0];
#pragma unroll
        for (int j = 1; j < 16; ++j) m = fmaxf(m, red[j]);
        *wmaxp = m;
    }
}

// ---------- K3: MFMA scan (depth-3 prefetch) + rescore + fused epilogue ----------
__global__ __launch_bounds__(BLKT, 4)
void vq_scan(const float* __restrict__ h, const float* __restrict__ w,
             const unsigned short* __restrict__ wbf, const float* __restrict__ bsq,
             const float* __restrict__ wmaxp, float* __restrict__ out) {
    __shared__ float smin[WAVES][RPB];
    __shared__ float sthr[RPB];
    __shared__ float sAf[RPB];
    __shared__ int scnt[RPB];
    __shared__ int sclist[RPB][CMAX];
    __shared__ unsigned long long sbkey[RPB];

    const int tid = threadIdx.x;
    const int wv = tid >> 6, lane = tid & 63;
    const int l16 = lane & 15, lh = lane >> 4;
    const int rowbase = blockIdx.x * RPB;

    if (tid < RPB) { scnt[tid] = 0; sbkey[tid] = 0xFFFFFFFFFFFFFFFFULL; }

    // fused Af: frozen pairwise-8 for the block's 32 rows (threads 0..31)
    if (tid < RPB) {
        const float* row = h + (size_t)(rowbase + tid) * DDIM;
        float hr[DDIM];
#pragma unroll
        for (int i = 0; i < DDIM; i += 4) {
            float4 v = *reinterpret_cast<const float4*>(row + i);
            hr[i] = v.x; hr[i + 1] = v.y; hr[i + 2] = v.z; hr[i + 3] = v.w;
        }
        float s[8];
#pragma unroll
        for (int j = 0; j < 8; ++j) s[j] = __fmul_rn(hr[j], hr[j]);
#pragma unroll
        for (int i = 8; i < DDIM; i += 8)
#pragma unroll
            for (int j = 0; j < 8; ++j)
                s[j] = __fadd_rn(s[j], __fmul_rn(hr[i + j], hr[i + j]));
        sAf[tid] = __fadd_rn(__fadd_rn(__fadd_rn(s[0], s[1]), __fadd_rn(s[2], s[3])),
                             __fadd_rn(__fadd_rn(s[4], s[5]), __fadd_rn(s[6], s[7])));
    }

    // A-frags (h rows, bf16) — layout validated R10/R11
    bf16x8 afr[2][2];
#pragma unroll
    for (int mt = 0; mt < 2; ++mt) {
        const float* hrow = h + ((size_t)(rowbase + mt * 16 + l16)) * DDIM;
#pragma unroll
        for (int dh = 0; dh < 2; ++dh) {
            float4 a = *reinterpret_cast<const float4*>(hrow + dh * 32 + lh * 8);
            float4 bq = *reinterpret_cast<const float4*>(hrow + dh * 32 + lh * 8 + 4);
            union { bf16x8 v; unsigned short u[8]; } pk;
            pk.u[0] = f2bf(a.x); pk.u[1] = f2bf(a.y); pk.u[2] = f2bf(a.z); pk.u[3] = f2bf(a.w);
            pk.u[4] = f2bf(bq.x); pk.u[5] = f2bf(bq.y); pk.u[6] = f2bf(bq.z); pk.u[7] = f2bf(bq.w);
            afr[mt][dh] = pk.v;
        }
    }

    // ---- pass A: depth-3 rotating prefetch of wbf tiles; MFMA; mins; val cache ----
    float pmin[8];
#pragma unroll
    for (int j = 0; j < 8; ++j) pmin[j] = INFINITY;
    unsigned vals[NTW][2][2];     // static-indexed via full unroll

    bf16x8 pb0[3], pb1[3];
    float pbq[3];
#pragma unroll
    for (int q = 0; q < 3; ++q) {
        const int nt = q * WAVES + wv;
        const unsigned short* wrow = wbf + (size_t)(nt * 16 + l16) * DDIM;
        pb0[q] = *reinterpret_cast<const bf16x8*>(wrow + lh * 8);
        pb1[q] = *reinterpret_cast<const bf16x8*>(wrow + 32 + lh * 8);
        pbq[q] = bsq[nt * 16 + l16];
    }

#pragma unroll
    for (int no = 0; no < NTW; ++no) {
        const int s = no % 3;
        bf16x8 bfr0 = pb0[s], bfr1 = pb1[s];
        float bq = pbq[s];
        if (no + 3 < NTW) {   // reissue slot with tile no+3 (consumed 3 iters later)
            const int nt = (no + 3) * WAVES + wv;
            const unsigned short* wrow = wbf + (size_t)(nt * 16 + l16) * DDIM;
            pb0[s] = *reinterpret_cast<const bf16x8*>(wrow + lh * 8);
            pb1[s] = *reinterpret_cast<const bf16x8*>(wrow + 32 + lh * 8);
            pbq[s] = bsq[nt * 16 + l16];
        }
#pragma unroll
        for (int mt = 0; mt < 2; ++mt) {
            f32x4 acc = {0.f, 0.f, 0.f, 0.f};
            acc = __builtin_amdgcn_mfma_f32_16x16x32_bf16(afr[mt][0], bfr0, acc, 0, 0, 0);
            acc = __builtin_amdgcn_mfma_f32_16x16x32_bf16(afr[mt][1], bfr1, acc, 0, 0, 0);
            float v0 = bq - (acc[0] + acc[0]);
            float v1 = bq - (acc[1] + acc[1]);
            float v2 = bq - (acc[2] + acc[2]);
            float v3 = bq - (acc[3] + acc[3]);
            pmin[mt * 4 + 0] = fminf(pmin[mt * 4 + 0], v0);
            pmin[mt * 4 + 1] = fminf(pmin[mt * 4 + 1], v1);
            pmin[mt * 4 + 2] = fminf(pmin[mt * 4 + 2], v2);
            pmin[mt * 4 + 3] = fminf(pmin[mt * 4 + 3], v3);
            vals[no][mt][0] = (unsigned)f2bf(v0) | ((unsigned)f2bf(v1) << 16);
            vals[no][mt][1] = (unsigned)f2bf(v2) | ((unsigned)f2bf(v3) << 16);
        }
    }

    // reduce mins over the 16 l16-lanes (same C-rows)
#pragma unroll
    for (int off = 1; off < 16; off <<= 1)
#pragma unroll
        for (int j = 0; j < 8; ++j) pmin[j] = fminf(pmin[j], __shfl_xor(pmin[j], off));
    if (l16 == 0) {
#pragma unroll
        for (int mt = 0; mt < 2; ++mt)
#pragma unroll
            for (int i = 0; i < 4; ++i)
                smin[wv][mt * 16 + lh * 4 + i] = pmin[mt * 4 + i];
    }
    __syncthreads();

    if (tid < RPB) {
        float m = smin[0][tid];
#pragma unroll
        for (int q = 1; q < WAVES; ++q) m = fminf(m, smin[q][tid]);
        sthr[tid] = m + sqrtf(sAf[tid]) * 1.001f * (*wmaxp) * 0.03125f + 1e-3f;  // validated margin
    }
    __syncthreads();

    float tr[8];
#pragma unroll
    for (int mt = 0; mt < 2; ++mt)
#pragma unroll
        for (int i = 0; i < 4; ++i) tr[mt * 4 + i] = sthr[mt * 16 + lh * 4 + i];

    // ---- candidate scan from registers ----
#pragma unroll
    for (int no = 0; no < NTW; ++no) {
        const int kk = (no * WAVES + wv) * 16 + l16;
#pragma unroll
        for (int mt = 0; mt < 2; ++mt) {
#pragma unroll
            for (int p = 0; p < 2; ++p) {
                unsigned u = vals[no][mt][p];
                float vlo = bflo2f(u), vhi = bfhi2f(u);
                if (vlo <= tr[mt * 4 + 2 * p]) {
                    int row = mt * 16 + lh * 4 + 2 * p;
                    int slot = atomicAdd(&scnt[row], 1);
                    if (slot < CMAX) sclist[row][slot] = kk;
                }
                if (vhi <= tr[mt * 4 + 2 * p + 1]) {
                    int row = mt * 16 + lh * 4 + 2 * p + 1;
                    int slot = atomicAdd(&scnt[row], 1);
                    if (slot < CMAX) sclist[row][slot] = kk;
                }
            }
        }
    }
    __syncthreads();

    // ---- rescore: 16 threads/row, exact frozen chain, atomicMin key ----
    {
        const int row = tid >> 4;
        const int s0 = tid & 15;
        const int cnt = scnt[row];
        if (cnt <= CMAX && s0 < cnt) {
            const size_t ng = (size_t)rowbase + row;
            const float Af = sAf[row];
            const float* hrow = h + ng * DDIM;
            float hreg[DDIM];
#pragma unroll
            for (int i = 0; i < DDIM; i += 4) {
                float4 v = *reinterpret_cast<const float4*>(hrow + i);
                hreg[i] = v.x; hreg[i + 1] = v.y; hreg[i + 2] = v.z; hreg[i + 3] = v.w;
            }
            for (int slot = s0; slot < cnt; slot += 16) {
                int k = sclist[row][slot];
                const float* wr = w + (size_t)k * DDIM;
                float acc = 0.f;
#pragma unroll
                for (int i = 0; i < DDIM; i += 4) {
                    float4 x = *reinterpret_cast<const float4*>(wr + i);
                    acc = fmaf(hreg[i + 0], x.x, acc);
                    acc = fmaf(hreg[i + 1], x.y, acc);
                    acc = fmaf(hreg[i + 2], x.z, acc);
                    acc = fmaf(hreg[i + 3], x.w, acc);
                }
                float d = __fsub_rn(__fadd_rn(Af, bsq[k]), __fadd_rn(acc, acc));
                unsigned long long key = ((unsigned long long)fsort(d) << 32) | (unsigned)k;
                atomicMin(&sbkey[row], key);
            }
        }
    }
    // overflow fallback (deterministic; effectively never taken)
#pragma unroll 1
    for (int r = 0; r < RPB; ++r) {
        if (scnt[r] > CMAX) {
            const size_t ng = (size_t)rowbase + r;
            const float Af = sAf[r];
            const float* hrow = h + ng * DDIM;
            float hreg[DDIM];
#pragma unroll
            for (int i = 0; i < DDIM; i += 4) {
                float4 v = *reinterpret_cast<const float4*>(hrow + i);
                hreg[i] = v.x; hreg[i + 1] = v.y; hreg[i + 2] = v.z; hreg[i + 3] = v.w;
            }
            for (int k = tid; k < KCB; k += BLKT) {
                const float* wr = w + (size_t)k * DDIM;
                float acc = 0.f;
#pragma unroll
                for (int i = 0; i < DDIM; i += 4) {
                    float4 x = *reinterpret_cast<const float4*>(wr + i);
                    acc = fmaf(hreg[i + 0], x.x, acc);
                    acc = fmaf(hreg[i + 1], x.y, acc);
                    acc = fmaf(hreg[i + 2], x.z, acc);
                    acc = fmaf(hreg[i + 3], x.w, acc);
                }
                float d = __fsub_rn(__fadd_rn(Af, bsq[k]), __fadd_rn(acc, acc));
                unsigned long long key = ((unsigned long long)fsort(d) << 32) | (unsigned)k;
                atomicMin(&sbkey[r], key);
            }
        }
    }
    __syncthreads();

    // ---- fused epilogue ----
    // idx output
    if (tid < RPB)
        out[NQ + rowbase + tid] = (float)(unsigned)(sbkey[tid] & 0xFFFFFFFFu);

    // qst: 512 threads x 1 float4 (row = tid>>4, quad = tid&15); ops identical to
    // the validated K4: d = fl(q - h), o = fl(h + d) — elementwise, order-free
    {
        const int row = tid >> 4;
        const int c4 = tid & 15;
        const int bk = (int)(unsigned)(sbkey[row] & 0xFFFFFFFFu);
        const size_t ng = (size_t)rowbase + row;
        float4 hq = *reinterpret_cast<const float4*>(h + ng * DDIM + 4 * c4);
        float4 wq = *reinterpret_cast<const float4*>(w + (size_t)bk * DDIM + 4 * c4);
        float4 o;
        o.x = __fadd_rn(hq.x, __fsub_rn(wq.x, hq.x));
        o.y = __fadd_rn(hq.y, __fsub_rn(wq.y, hq.y));
        o.z = __fadd_rn(hq.z, __fsub_rn(wq.z, hq.z));
        o.w = __fadd_rn(hq.w, __fsub_rn(wq.w, hq.w));
        *reinterpret_cast<float4*>(out + ng * DDIM + 4 * c4) = o;
    }

    // loss: threads 0..31, one row each — verbatim frozen recipe (validated R2)
    if (tid < RPB) {
        const int bk = (int)(unsigned)(sbkey[tid] & 0xFFFFFFFFu);
        const size_t ng = (size_t)rowbase + tid;
        const float* hrow = h + ng * DDIM;
        const float* qrow = w + (size_t)bk * DDIM;
        float hr[DDIM];
#pragma unroll
        for (int i = 0; i < DDIM; i += 4) {
            float4 v = *reinterpret_cast<const float4*>(hrow + i);
            hr[i] = v.x; hr[i + 1] = v.y; hr[i + 2] = v.z; hr[i + 3] = v.w;
        }
        float r2[8];
#pragma unroll
        for (int c = 0; c < 8; ++c) {
            float4 qa = *reinterpret_cast<const float4*>(qrow + 8 * c);
            float4 qb = *reinterpret_cast<const float4*>(qrow + 8 * c + 4);
            float d0 = __fsub_rn(qa.x, hr[8 * c + 0]);
            float d1 = __fsub_rn(qa.y, hr[8 * c + 1]);
            float d2 = __fsub_rn(qa.z, hr[8 * c + 2]);
            float d3 = __fsub_rn(qa.w, hr[8 * c + 3]);
            float d4 = __fsub_rn(qb.x, hr[8 * c + 4]);
            float d5 = __fsub_rn(qb.y, hr[8 * c + 5]);
            float d6 = __fsub_rn(qb.z, hr[8 * c + 6]);
            float d7 = __fsub_rn(qb.w, hr[8 * c + 7]);
            if (c == 0) {
                r2[0] = __fmul_rn(d0, d0); r2[1] = __fmul_rn(d1, d1);
                r2[2] = __fmul_rn(d2, d2); r2[3] = __fmul_rn(d3, d3);
                r2[4] = __fmul_rn(d4, d4); r2[5] = __fmul_rn(d5, d5);
                r2[6] = __fmul_rn(d6, d6); r2[7] = __fmul_rn(d7, d7);
            } else {
                r2[0] = __fadd_rn(r2[0], __fmul_rn(d0, d0));
                r2[1] = __fadd_rn(r2[1], __fmul_rn(d1, d1));
                r2[2] = __fadd_rn(r2[2], __fmul_rn(d2, d2));
                r2[3] = __fadd_rn(r2[3], __fmul_rn(d3, d3));
                r2[4] = __fadd_rn(r2[4], __fmul_rn(d4, d4));
                r2[5] = __fadd_rn(r2[5], __fmul_rn(d5, d5));
                r2[6] = __fadd_rn(r2[6], __fmul_rn(d6, d6));
                r2[7] = __fadd_rn(r2[7], __fmul_rn(d7, d7));
            }
        }
        float S = __fadd_rn(__fadd_rn(__fadd_rn(r2[0], r2[1]), __fadd_rn(r2[2], r2[3])),
                            __fadd_rn(__fadd_rn(r2[4], r2[5]), __fadd_rn(r2[6], r2[7])));
        float m = __fmul_rn(S, 0.015625f);
        out[NQ + NROWS + ng] = __fadd_rn(__fmul_rn(m, 0.1f), __fmul_rn(m, 0.2f));
    }
}

extern "C" void kernel_launch(void* const* d_in, const int* in_sizes, int n_in,
                              void* d_out, int out_size, void* d_ws, size_t ws_size,
                              hipStream_t stream) {
    (void)in_sizes; (void)n_in; (void)out_size; (void)ws_size;
    const float* h = (const float*)d_in[0];
    const float* w = (const float*)d_in[1];
    float* out = (float*)d_out;

    char* ws = (char*)d_ws;
    float* bsq = (float*)ws;                               // 4 KB
    float* wmaxp = (float*)(ws + 4096);                    // 16 B
    unsigned short* wbf = (unsigned short*)(ws + 8192);    // 128 KB

    prep_w<<<1, 1024, 0, stream>>>(w, bsq, wbf, wmaxp);
    vq_scan<<<NROWS / RPB, BLKT, 0, stream>>>(h, w, wbf, bsq, wmaxp, out);
}

// Round 14
// 350.112 us; speedup vs baseline: 1.5884x; 1.0833x over previous
//
#include <hip/hip_runtime.h>
#include <math.h>

#define NROWS (512 * 512)
#define KCB   1024
#define DDIM  64
#define NQ    ((size_t)NROWS * DDIM)
#define RPW   32            // rows per wave
#define CMAX  16            // candidate cap per row (avg ~3; overflow -> exact full scan)
#define WAVES 8
#define BLKT  512
#define NT    (KCB / 16)    // 64 k-tiles, all per wave

typedef __attribute__((ext_vector_type(8))) short bf16x8;
typedef __attribute__((ext_vector_type(4))) float f32x4;

__device__ __forceinline__ unsigned short f2bf(float x) {
    unsigned u = __float_as_uint(x);
    u = u + 0x7FFFu + ((u >> 16) & 1u);
    return (unsigned short)(u >> 16);
}
__device__ __forceinline__ unsigned fsort(float d) {   // monotonic f32 -> u32
    unsigned u = __float_as_uint(d);
    return (u & 0x80000000u) ? ~u : (u | 0x80000000u);
}

// ---------- K1: frozen wsq + w->bf16 + wmax ----------
__global__ __launch_bounds__(1024)
void prep_w(const float* __restrict__ w, float* __restrict__ bsq,
            unsigned short* __restrict__ wbf, float* __restrict__ wmaxp) {
    __shared__ float red[16];
    const int k = threadIdx.x;
    const float* row = w + (size_t)k * DDIM;
    float r[8];
#pragma unroll
    for (int j = 0; j < 8; ++j) r[j] = __fmul_rn(row[j], row[j]);
#pragma unroll
    for (int i = 8; i < DDIM; i += 8)
#pragma unroll
        for (int j = 0; j < 8; ++j)
            r[j] = __fadd_rn(r[j], __fmul_rn(row[i + j], row[i + j]));
    float b = __fadd_rn(__fadd_rn(__fadd_rn(r[0], r[1]), __fadd_rn(r[2], r[3])),
                        __fadd_rn(__fadd_rn(r[4], r[5]), __fadd_rn(r[6], r[7])));
    bsq[k] = b;
    unsigned* dst = (unsigned*)(wbf + (size_t)k * DDIM);
#pragma unroll
    for (int j = 0; j < 32; ++j)
        dst[j] = (unsigned)f2bf(row[2 * j]) | ((unsigned)f2bf(row[2 * j + 1]) << 16);
    float v = sqrtf(b) * 1.02f;
#pragma unroll
    for (int off = 1; off < 64; off <<= 1) v = fmaxf(v, __shfl_xor(v, off));
    if ((threadIdx.x & 63) == 0) red[threadIdx.x >> 6] = v;
    __syncthreads();
    if (threadIdx.x == 0) {
        float m = red[0];
#pragma unroll
        for (int j = 1; j < 16; ++j) m = fmaxf(m, red[j]);
        *wmaxp = m;
    }
}

// ---------- K3: barrier-free per-wave scan + rescore + fused epilogue ----------
__global__ __launch_bounds__(BLKT, 4)
void vq_scan(const float* __restrict__ h, const float* __restrict__ w,
             const unsigned short* __restrict__ wbf, const float* __restrict__ bsq,
             const float* __restrict__ wmaxp, float* __restrict__ out) {
    __shared__ int scnt[WAVES][RPW];
    __shared__ int sclist[WAVES][RPW][CMAX];
    __shared__ unsigned long long sbkey[WAVES][RPW];

    const int tid = threadIdx.x;
    const int wv = tid >> 6, lane = tid & 63;
    const int l16 = lane & 15, lh = lane >> 4;
    const int rowbase = blockIdx.x * (WAVES * RPW) + wv * RPW;   // this wave's 32 rows

    if (lane < RPW) { scnt[wv][lane] = 0; sbkey[wv][lane] = 0xFFFFFFFFFFFFFFFFULL; }

    // Af: frozen pairwise-8 (lane r computes row r; feeds exact rescore dist)
    float af = 0.f;
    if (lane < RPW) {
        const float* row = h + (size_t)(rowbase + lane) * DDIM;
        float hr[DDIM];
#pragma unroll
        for (int i = 0; i < DDIM; i += 4) {
            float4 v = *reinterpret_cast<const float4*>(row + i);
            hr[i] = v.x; hr[i + 1] = v.y; hr[i + 2] = v.z; hr[i + 3] = v.w;
        }
        float s[8];
#pragma unroll
        for (int j = 0; j < 8; ++j) s[j] = __fmul_rn(hr[j], hr[j]);
#pragma unroll
        for (int i = 8; i < DDIM; i += 8)
#pragma unroll
            for (int j = 0; j < 8; ++j)
                s[j] = __fadd_rn(s[j], __fmul_rn(hr[i + j], hr[i + j]));
        af = __fadd_rn(__fadd_rn(__fadd_rn(s[0], s[1]), __fadd_rn(s[2], s[3])),
                       __fadd_rn(__fadd_rn(s[4], s[5]), __fadd_rn(s[6], s[7])));
    }

    // A-frags (h rows, bf16) — layout validated R10-R13
    bf16x8 afr[2][2];
#pragma unroll
    for (int mt = 0; mt < 2; ++mt) {
        const float* hrow = h + ((size_t)(rowbase + mt * 16 + l16)) * DDIM;
#pragma unroll
        for (int dh = 0; dh < 2; ++dh) {
            float4 a = *reinterpret_cast<const float4*>(hrow + dh * 32 + lh * 8);
            float4 bq = *reinterpret_cast<const float4*>(hrow + dh * 32 + lh * 8 + 4);
            union { bf16x8 v; unsigned short u[8]; } pk;
            pk.u[0] = f2bf(a.x); pk.u[1] = f2bf(a.y); pk.u[2] = f2bf(a.z); pk.u[3] = f2bf(a.w);
            pk.u[4] = f2bf(bq.x); pk.u[5] = f2bf(bq.y); pk.u[6] = f2bf(bq.z); pk.u[7] = f2bf(bq.w);
            afr[mt][dh] = pk.v;
        }
    }

    // ---- pass A: all 64 k-tiles, depth-2 register prefetch, per-lane mins ----
    float pmin[8];
#pragma unroll
    for (int j = 0; j < 8; ++j) pmin[j] = INFINITY;

    bf16x8 pb0[2], pb1[2];
    float pbq[2];
#pragma unroll
    for (int q = 0; q < 2; ++q) {
        const unsigned short* wrow = wbf + (size_t)(q * 16 + l16) * DDIM;
        pb0[q] = *reinterpret_cast<const bf16x8*>(wrow + lh * 8);
        pb1[q] = *reinterpret_cast<const bf16x8*>(wrow + 32 + lh * 8);
        pbq[q] = bsq[q * 16 + l16];
    }
#pragma unroll 4
    for (int no = 0; no < NT; ++no) {
        const int s = no & 1;
        bf16x8 bfr0 = pb0[s], bfr1 = pb1[s];
        float bq = pbq[s];
        {   // branchless reload (clamped dup for last 2 iters, never consumed)
            const int ntn = (no + 2 < NT) ? (no + 2) : (NT - 1);
            const unsigned short* wrow = wbf + (size_t)(ntn * 16 + l16) * DDIM;
            pb0[s] = *reinterpret_cast<const bf16x8*>(wrow + lh * 8);
            pb1[s] = *reinterpret_cast<const bf16x8*>(wrow + 32 + lh * 8);
            pbq[s] = bsq[ntn * 16 + l16];
        }
#pragma unroll
        for (int mt = 0; mt < 2; ++mt) {
            f32x4 acc = {0.f, 0.f, 0.f, 0.f};
            acc = __builtin_amdgcn_mfma_f32_16x16x32_bf16(afr[mt][0], bfr0, acc, 0, 0, 0);
            acc = __builtin_amdgcn_mfma_f32_16x16x32_bf16(afr[mt][1], bfr1, acc, 0, 0, 0);
#pragma unroll
            for (int i = 0; i < 4; ++i)
                pmin[mt * 4 + i] = fminf(pmin[mt * 4 + i], bq - (acc[i] + acc[i]));
        }
    }

    // in-wave butterfly over the 16 l16-lanes (all lanes end with the min)
#pragma unroll
    for (int off = 1; off < 16; off <<= 1)
#pragma unroll
        for (int j = 0; j < 8; ++j) pmin[j] = fminf(pmin[j], __shfl_xor(pmin[j], off));

    // thresholds for this lane's 8 C-rows (validated margin formula)
    const float wmaxv = *wmaxp;
    float tr[8];
#pragma unroll
    for (int mt = 0; mt < 2; ++mt)
#pragma unroll
        for (int i = 0; i < 4; ++i) {
            float Afr = __shfl(af, mt * 16 + lh * 4 + i);
            tr[mt * 4 + i] = pmin[mt * 4 + i] + sqrtf(Afr) * 1.001f * wmaxv * 0.03125f + 1e-3f;
        }

    // ---- pass B: recompute (bitwise == pass A), collect candidates ----
#pragma unroll
    for (int q = 0; q < 2; ++q) {
        const unsigned short* wrow = wbf + (size_t)(q * 16 + l16) * DDIM;
        pb0[q] = *reinterpret_cast<const bf16x8*>(wrow + lh * 8);
        pb1[q] = *reinterpret_cast<const bf16x8*>(wrow + 32 + lh * 8);
        pbq[q] = bsq[q * 16 + l16];
    }
#pragma unroll 4
    for (int no = 0; no < NT; ++no) {
        const int s = no & 1;
        bf16x8 bfr0 = pb0[s], bfr1 = pb1[s];
        float bq = pbq[s];
        {
            const int ntn = (no + 2 < NT) ? (no + 2) : (NT - 1);
            const unsigned short* wrow = wbf + (size_t)(ntn * 16 + l16) * DDIM;
            pb0[s] = *reinterpret_cast<const bf16x8*>(wrow + lh * 8);
            pb1[s] = *reinterpret_cast<const bf16x8*>(wrow + 32 + lh * 8);
            pbq[s] = bsq[ntn * 16 + l16];
        }
        const int kk = no * 16 + l16;
#pragma unroll
        for (int mt = 0; mt < 2; ++mt) {
            f32x4 acc = {0.f, 0.f, 0.f, 0.f};
            acc = __builtin_amdgcn_mfma_f32_16x16x32_bf16(afr[mt][0], bfr0, acc, 0, 0, 0);
            acc = __builtin_amdgcn_mfma_f32_16x16x32_bf16(afr[mt][1], bfr1, acc, 0, 0, 0);
#pragma unroll
            for (int i = 0; i < 4; ++i) {
                float val = bq - (acc[i] + acc[i]);
                if (val <= tr[mt * 4 + i]) {
                    int row = mt * 16 + lh * 4 + i;
                    int slot = atomicAdd(&scnt[wv][row], 1);
                    if (slot < CMAX) sclist[wv][row][slot] = kk;
                }
            }
        }
    }
    __builtin_amdgcn_wave_barrier();

    // ---- rescore: 2 lanes/row, exact frozen chain, (d,k) atomicMin key ----
    {
        const int row = lane >> 1;
        const int s0 = lane & 1;
        const float Afr = __shfl(af, row);     // pre-divergence shfl
        const int cnt = scnt[wv][row];
        if (cnt <= CMAX && s0 < cnt) {
            const size_t ng = (size_t)rowbase + row;
            const float* hrow = h + ng * DDIM;
            float hreg[DDIM];
#pragma unroll
            for (int i = 0; i < DDIM; i += 4) {
                float4 v = *reinterpret_cast<const float4*>(hrow + i);
                hreg[i] = v.x; hreg[i + 1] = v.y; hreg[i + 2] = v.z; hreg[i + 3] = v.w;
            }
            for (int slot = s0; slot < cnt; slot += 2) {
                int k = sclist[wv][row][slot];
                const float* wr = w + (size_t)k * DDIM;
                float acc = 0.f;
#pragma unroll
                for (int i = 0; i < DDIM; i += 4) {
                    float4 x = *reinterpret_cast<const float4*>(wr + i);
                    acc = fmaf(hreg[i + 0], x.x, acc);
                    acc = fmaf(hreg[i + 1], x.y, acc);
                    acc = fmaf(hreg[i + 2], x.z, acc);
                    acc = fmaf(hreg[i + 3], x.w, acc);
                }
                float d = __fsub_rn(__fadd_rn(Afr, bsq[k]), __fadd_rn(acc, acc));
                unsigned long long key = ((unsigned long long)fsort(d) << 32) | (unsigned)k;
                atomicMin(&sbkey[wv][row], key);
            }
        }
    }
    // overflow fallback (exact full scan, wave-wide; rare)
#pragma unroll 1
    for (int r = 0; r < RPW; ++r) {
        const float Afr = __shfl(af, r);
        if (scnt[wv][r] > CMAX) {
            const size_t ng = (size_t)rowbase + r;
            const float* hrow = h + ng * DDIM;
            float hreg[DDIM];
#pragma unroll
            for (int i = 0; i < DDIM; i += 4) {
                float4 v = *reinterpret_cast<const float4*>(hrow + i);
                hreg[i] = v.x; hreg[i + 1] = v.y; hreg[i + 2] = v.z; hreg[i + 3] = v.w;
            }
            for (int k = lane; k < KCB; k += 64) {
                const float* wr = w + (size_t)k * DDIM;
                float acc = 0.f;
#pragma unroll
                for (int i = 0; i < DDIM; i += 4) {
                    float4 x = *reinterpret_cast<const float4*>(wr + i);
                    acc = fmaf(hreg[i + 0], x.x, acc);
                    acc = fmaf(hreg[i + 1], x.y, acc);
                    acc = fmaf(hreg[i + 2], x.z, acc);
                    acc = fmaf(hreg[i + 3], x.w, acc);
                }
                float d = __fsub_rn(__fadd_rn(Afr, bsq[k]), __fadd_rn(acc, acc));
                unsigned long long key = ((unsigned long long)fsort(d) << 32) | (unsigned)k;
                atomicMin(&sbkey[wv][r], key);
            }
        }
    }
    __builtin_amdgcn_wave_barrier();

    // ---- fused outputs (per wave) ----
    if (lane < RPW)
        out[NQ + rowbase + lane] = (float)(unsigned)(sbkey[wv][lane] & 0xFFFFFFFFu);

    // qst: 8 float4/lane; ops identical to validated K4 (d=fl(q-h), o=fl(h+d))
#pragma unroll
    for (int q = 0; q < 8; ++q) {
        const int idx = q * 64 + lane;         // 0..511 float4s of this wave's rows
        const int row = idx >> 4, c4 = idx & 15;
        const int bk = (int)(unsigned)(sbkey[wv][row] & 0xFFFFFFFFu);
        const size_t ng = (size_t)rowbase + row;
        float4 hq = *reinterpret_cast<const float4*>(h + ng * DDIM + 4 * c4);
        float4 wq = *reinterpret_cast<const float4*>(w + (size_t)bk * DDIM + 4 * c4);
        float4 o;
        o.x = __fadd_rn(hq.x, __fsub_rn(wq.x, hq.x));
        o.y = __fadd_rn(hq.y, __fsub_rn(wq.y, hq.y));
        o.z = __fadd_rn(hq.z, __fsub_rn(wq.z, hq.z));
        o.w = __fadd_rn(hq.w, __fsub_rn(wq.w, hq.w));
        *reinterpret_cast<float4*>(out + ng * DDIM + 4 * c4) = o;
    }

    // loss: lane<32, one row each — verbatim frozen recipe (validated R2)
    if (lane < RPW) {
        const int bk = (int)(unsigned)(sbkey[wv][lane] & 0xFFFFFFFFu);
        const size_t ng = (size_t)rowbase + lane;
        const float* hrow = h + ng * DDIM;
        const float* qrow = w + (size_t)bk * DDIM;
        float hr[DDIM];
#pragma unroll
        for (int i = 0; i < DDIM; i += 4) {
            float4 v = *reinterpret_cast<const float4*>(hrow + i);
            hr[i] = v.x; hr[i + 1] = v.y; hr[i + 2] = v.z; hr[i + 3] = v.w;
        }
        float r2[8];
#pragma unroll
        for (int c = 0; c < 8; ++c) {
            float4 qa = *reinterpret_cast<const float4*>(qrow + 8 * c);
            float4 qb = *reinterpret_cast<const float4*>(qrow + 8 * c + 4);
            float d0 = __fsub_rn(qa.x, hr[8 * c + 0]);
            float d1 = __fsub_rn(qa.y, hr[8 * c + 1]);
            float d2 = __fsub_rn(qa.z, hr[8 * c + 2]);
            float d3 = __fsub_rn(qa.w, hr[8 * c + 3]);
            float d4 = __fsub_rn(qb.x, hr[8 * c + 4]);
            float d5 = __fsub_rn(qb.y, hr[8 * c + 5]);
            float d6 = __fsub_rn(qb.z, hr[8 * c + 6]);
            float d7 = __fsub_rn(qb.w, hr[8 * c + 7]);
            if (c == 0) {
                r2[0] = __fmul_rn(d0, d0); r2[1] = __fmul_rn(d1, d1);
                r2[2] = __fmul_rn(d2, d2); r2[3] = __fmul_rn(d3, d3);
                r2[4] = __fmul_rn(d4, d4); r2[5] = __fmul_rn(d5, d5);
                r2[6] = __fmul_rn(d6, d6); r2[7] = __fmul_rn(d7, d7);
            } else {
                r2[0] = __fadd_rn(r2[0], __fmul_rn(d0, d0));
                r2[1] = __fadd_rn(r2[1], __fmul_rn(d1, d1));
                r2[2] = __fadd_rn(r2[2], __fmul_rn(d2, d2));
                r2[3] = __fadd_rn(r2[3], __fmul_rn(d3, d3));
                r2[4] = __fadd_rn(r2[4], __fmul_rn(d4, d4));
                r2[5] = __fadd_rn(r2[5], __fmul_rn(d5, d5));
                r2[6] = __fadd_rn(r2[6], __fmul_rn(d6, d6));
                r2[7] = __fadd_rn(r2[7], __fmul_rn(d7, d7));
            }
        }
        float S = __fadd_rn(__fadd_rn(__fadd_rn(r2[0], r2[1]), __fadd_rn(r2[2], r2[3])),
                            __fadd_rn(__fadd_rn(r2[4], r2[5]), __fadd_rn(r2[6], r2[7])));
        float m = __fmul_rn(S, 0.015625f);
        out[NQ + NROWS + ng] = __fadd_rn(__fmul_rn(m, 0.1f), __fmul_rn(m, 0.2f));
    }
}

extern "C" void kernel_launch(void* const* d_in, const int* in_sizes, int n_in,
                              void* d_out, int out_size, void* d_ws, size_t ws_size,
                              hipStream_t stream) {
    (void)in_sizes; (void)n_in; (void)out_size; (void)ws_size;
    const float* h = (const float*)d_in[0];
    const float* w = (const float*)d_in[1];
    float* out = (float*)d_out;

    char* ws = (char*)d_ws;
    float* bsq = (float*)ws;                               // 4 KB
    float* wmaxp = (float*)(ws + 4096);                    // 16 B
    unsigned short* wbf = (unsigned short*)(ws + 8192);    // 128 KB

    prep_w<<<1, 1024, 0, stream>>>(w, bsq, wbf, wmaxp);
    vq_scan<<<NROWS / (WAVES * RPW), BLKT, 0, stream>>>(h, w, wbf, bsq, wmaxp, out);
}

// Round 15
// 286.088 us; speedup vs baseline: 1.9439x; 1.2238x over previous
//
#include <hip/hip_runtime.h>
#include <math.h>

#define NROWS (512 * 512)
#define KCB   1024
#define DDIM  64
#define NQ    ((size_t)NROWS * DDIM)
#define RPW   32            // rows per wave
#define CMAX  8             // candidate cap per row (typ. 1-3; overflow -> exact full scan)
#define WAVES 8
#define BLKT  512
#define KPH   512           // codes per LDS phase
#define NTPH  (KPH / 16)    // 32 k-tiles per phase

typedef __attribute__((ext_vector_type(8))) short bf16x8;
typedef __attribute__((ext_vector_type(4))) float f32x4;

__device__ __forceinline__ unsigned short f2bf(float x) {
    unsigned u = __float_as_uint(x);
    u = u + 0x7FFFu + ((u >> 16) & 1u);
    return (unsigned short)(u >> 16);
}
__device__ __forceinline__ unsigned fsort(float d) {   // monotonic f32 -> u32
    unsigned u = __float_as_uint(d);
    return (u & 0x80000000u) ? ~u : (u | 0x80000000u);
}

// ---------- K1: frozen wsq + w->bf16 + wmax ----------
__global__ __launch_bounds__(1024)
void prep_w(const float* __restrict__ w, float* __restrict__ bsq,
            unsigned short* __restrict__ wbf, float* __restrict__ wmaxp) {
    __shared__ float red[16];
    const int k = threadIdx.x;
    const float* row = w + (size_t)k * DDIM;
    float r[8];
#pragma unroll
    for (int j = 0; j < 8; ++j) r[j] = __fmul_rn(row[j], row[j]);
#pragma unroll
    for (int i = 8; i < DDIM; i += 8)
#pragma unroll
        for (int j = 0; j < 8; ++j)
            r[j] = __fadd_rn(r[j], __fmul_rn(row[i + j], row[i + j]));
    float b = __fadd_rn(__fadd_rn(__fadd_rn(r[0], r[1]), __fadd_rn(r[2], r[3])),
                        __fadd_rn(__fadd_rn(r[4], r[5]), __fadd_rn(r[6], r[7])));
    bsq[k] = b;
    unsigned* dst = (unsigned*)(wbf + (size_t)k * DDIM);
#pragma unroll
    for (int j = 0; j < 32; ++j)
        dst[j] = (unsigned)f2bf(row[2 * j]) | ((unsigned)f2bf(row[2 * j + 1]) << 16);
    float v = sqrtf(b) * 1.02f;
#pragma unroll
    for (int off = 1; off < 64; off <<= 1) v = fmaxf(v, __shfl_xor(v, off));
    if ((threadIdx.x & 63) == 0) red[threadIdx.x >> 6] = v;
    __syncthreads();
    if (threadIdx.x == 0) {
        float m = red[0];
#pragma unroll
        for (int j = 1; j < 16; ++j) m = fmaxf(m, red[j]);
        *wmaxp = m;
    }
}

// ---------- K3: LDS-staged swizzled scan + rescore + fused epilogue ----------
__global__ __launch_bounds__(BLKT, 4)
void vq_scan(const float* __restrict__ h, const float* __restrict__ w,
             const unsigned short* __restrict__ wbf, const float* __restrict__ bsq,
             const float* __restrict__ wmaxp, float* __restrict__ out) {
    // 64 KB swizzled codebook half: row lr (0..511) x 8 float4 chunks, chunk c
    // stored at s4[lr*8 + (c ^ (lr&7))]  (XOR involution, 16B granularity)
    __shared__ float4 s4[KPH * 8];
    __shared__ float sbsq[KPH];
    __shared__ int scnt[WAVES][RPW];
    __shared__ unsigned short sclist[WAVES][RPW][CMAX];
    __shared__ unsigned long long sbkey[WAVES][RPW];

    const int tid = threadIdx.x;
    const int wv = tid >> 6, lane = tid & 63;
    const int l16 = lane & 15, lh = lane >> 4;
    const int rowbase = blockIdx.x * (WAVES * RPW) + wv * RPW;   // wave's 32 rows

    if (lane < RPW) { scnt[wv][lane] = 0; sbkey[wv][lane] = 0xFFFFFFFFFFFFFFFFULL; }

    // Af: frozen pairwise-8 (lane r computes row r)
    float af = 0.f;
    if (lane < RPW) {
        const float* row = h + (size_t)(rowbase + lane) * DDIM;
        float hr[DDIM];
#pragma unroll
        for (int i = 0; i < DDIM; i += 4) {
            float4 v = *reinterpret_cast<const float4*>(row + i);
            hr[i] = v.x; hr[i + 1] = v.y; hr[i + 2] = v.z; hr[i + 3] = v.w;
        }
        float s[8];
#pragma unroll
        for (int j = 0; j < 8; ++j) s[j] = __fmul_rn(hr[j], hr[j]);
#pragma unroll
        for (int i = 8; i < DDIM; i += 8)
#pragma unroll
            for (int j = 0; j < 8; ++j)
                s[j] = __fadd_rn(s[j], __fmul_rn(hr[i + j], hr[i + j]));
        af = __fadd_rn(__fadd_rn(__fadd_rn(s[0], s[1]), __fadd_rn(s[2], s[3])),
                       __fadd_rn(__fadd_rn(s[4], s[5]), __fadd_rn(s[6], s[7])));
    }

    // A-frags (h rows, bf16) — layout validated R10-R14
    bf16x8 afr[2][2];
#pragma unroll
    for (int mt = 0; mt < 2; ++mt) {
        const float* hrow = h + ((size_t)(rowbase + mt * 16 + l16)) * DDIM;
#pragma unroll
        for (int dh = 0; dh < 2; ++dh) {
            float4 a = *reinterpret_cast<const float4*>(hrow + dh * 32 + lh * 8);
            float4 bq = *reinterpret_cast<const float4*>(hrow + dh * 32 + lh * 8 + 4);
            union { bf16x8 v; unsigned short u[8]; } pk;
            pk.u[0] = f2bf(a.x); pk.u[1] = f2bf(a.y); pk.u[2] = f2bf(a.z); pk.u[3] = f2bf(a.w);
            pk.u[4] = f2bf(bq.x); pk.u[5] = f2bf(bq.y); pk.u[6] = f2bf(bq.z); pk.u[7] = f2bf(bq.w);
            afr[mt][dh] = pk.v;
        }
    }

    // per-lane constant swizzled chunk indices (lr&7 == l16&7 since nt*16 ≡ 0 mod 8)
    const int sw = l16 & 7;
    const int C0 = lh ^ sw;         // chunk for d0..31
    const int C1 = (4 + lh) ^ sw;   // chunk for d32..63

    float pmin[8];
#pragma unroll
    for (int j = 0; j < 8; ++j) pmin[j] = INFINITY;

    const float4* g4all = reinterpret_cast<const float4*>(wbf);

    // ================== PASS A: mins (2 staged phases) ==================
#pragma unroll 1
    for (int ph = 0; ph < 2; ++ph) {
        const int k0 = ph * KPH;
        __syncthreads();   // protect previous phase readers before overwrite
        // stage: linear LDS write, inverse-permuted global read (rule-21 pair)
        const float4* g4 = g4all + (size_t)k0 * 8;
#pragma unroll
        for (int j = 0; j < 8; ++j) {
            int F = j * BLKT + tid;          // 0..4095 LDS float4 index
            int r = F >> 3, c = F & 7;
            s4[F] = g4[r * 8 + (c ^ (r & 7))];
        }
        sbsq[tid] = bsq[k0 + tid];
        __syncthreads();

        // depth-2 register prefetch from LDS
        float4 pb0[2], pb1[2];
        float pbq[2];
#pragma unroll
        for (int q = 0; q < 2; ++q) {
            const int lr = q * 16 + l16;
            pb0[q] = s4[lr * 8 + C0];
            pb1[q] = s4[lr * 8 + C1];
            pbq[q] = sbsq[lr];
        }
#pragma unroll 4
        for (int nt = 0; nt < NTPH; ++nt) {
            const int s = nt & 1;
            float4 b0 = pb0[s], b1 = pb1[s];
            float bq = pbq[s];
            {
                const int ntn = (nt + 2 < NTPH) ? (nt + 2) : (NTPH - 1);
                const int lr = ntn * 16 + l16;
                pb0[s] = s4[lr * 8 + C0];
                pb1[s] = s4[lr * 8 + C1];
                pbq[s] = sbsq[lr];
            }
            bf16x8 bfr0 = *reinterpret_cast<const bf16x8*>(&b0);
            bf16x8 bfr1 = *reinterpret_cast<const bf16x8*>(&b1);
#pragma unroll
            for (int mt = 0; mt < 2; ++mt) {
                f32x4 acc = {0.f, 0.f, 0.f, 0.f};
                acc = __builtin_amdgcn_mfma_f32_16x16x32_bf16(afr[mt][0], bfr0, acc, 0, 0, 0);
                acc = __builtin_amdgcn_mfma_f32_16x16x32_bf16(afr[mt][1], bfr1, acc, 0, 0, 0);
#pragma unroll
                for (int i = 0; i < 4; ++i)
                    pmin[mt * 4 + i] = fminf(pmin[mt * 4 + i], bq - (acc[i] + acc[i]));
            }
        }
    }

    // butterfly min over the 16 l16-lanes; thresholds (validated margin formula)
#pragma unroll
    for (int off = 1; off < 16; off <<= 1)
#pragma unroll
        for (int j = 0; j < 8; ++j) pmin[j] = fminf(pmin[j], __shfl_xor(pmin[j], off));
    const float wmaxv = *wmaxp;
    float tr[8];
#pragma unroll
    for (int mt = 0; mt < 2; ++mt)
#pragma unroll
        for (int i = 0; i < 4; ++i) {
            float Afr = __shfl(af, mt * 16 + lh * 4 + i);
            tr[mt * 4 + i] = pmin[mt * 4 + i] + sqrtf(Afr) * 1.001f * wmaxv * 0.03125f + 1e-3f;
        }

    // ================== PASS B: candidates (re-staged phases) ==================
#pragma unroll 1
    for (int ph = 0; ph < 2; ++ph) {
        const int k0 = ph * KPH;
        __syncthreads();
        const float4* g4 = g4all + (size_t)k0 * 8;
#pragma unroll
        for (int j = 0; j < 8; ++j) {
            int F = j * BLKT + tid;
            int r = F >> 3, c = F & 7;
            s4[F] = g4[r * 8 + (c ^ (r & 7))];
        }
        sbsq[tid] = bsq[k0 + tid];
        __syncthreads();

        float4 pb0[2], pb1[2];
        float pbq[2];
#pragma unroll
        for (int q = 0; q < 2; ++q) {
            const int lr = q * 16 + l16;
            pb0[q] = s4[lr * 8 + C0];
            pb1[q] = s4[lr * 8 + C1];
            pbq[q] = sbsq[lr];
        }
#pragma unroll 4
        for (int nt = 0; nt < NTPH; ++nt) {
            const int s = nt & 1;
            float4 b0 = pb0[s], b1 = pb1[s];
            float bq = pbq[s];
            {
                const int ntn = (nt + 2 < NTPH) ? (nt + 2) : (NTPH - 1);
                const int lr = ntn * 16 + l16;
                pb0[s] = s4[lr * 8 + C0];
                pb1[s] = s4[lr * 8 + C1];
                pbq[s] = sbsq[lr];
            }
            bf16x8 bfr0 = *reinterpret_cast<const bf16x8*>(&b0);
            bf16x8 bfr1 = *reinterpret_cast<const bf16x8*>(&b1);
            const int kk = k0 + nt * 16 + l16;
#pragma unroll
            for (int mt = 0; mt < 2; ++mt) {
                f32x4 acc = {0.f, 0.f, 0.f, 0.f};
                acc = __builtin_amdgcn_mfma_f32_16x16x32_bf16(afr[mt][0], bfr0, acc, 0, 0, 0);
                acc = __builtin_amdgcn_mfma_f32_16x16x32_bf16(afr[mt][1], bfr1, acc, 0, 0, 0);
#pragma unroll
                for (int i = 0; i < 4; ++i) {
                    float val = bq - (acc[i] + acc[i]);
                    if (val <= tr[mt * 4 + i]) {
                        int row = mt * 16 + lh * 4 + i;
                        int slot = atomicAdd(&scnt[wv][row], 1);
                        if (slot < CMAX) sclist[wv][row][slot] = (unsigned short)kk;
                    }
                }
            }
        }
    }
    __builtin_amdgcn_wave_barrier();

    // ---- rescore: 2 lanes/row, exact frozen chain, (d,k) atomicMin key ----
    {
        const int row = lane >> 1;
        const int s0 = lane & 1;
        const float Afr = __shfl(af, row);
        const int cnt = scnt[wv][row];
        if (cnt <= CMAX && s0 < cnt) {
            const size_t ng = (size_t)rowbase + row;
            const float* hrow = h + ng * DDIM;
            float hreg[DDIM];
#pragma unroll
            for (int i = 0; i < DDIM; i += 4) {
                float4 v = *reinterpret_cast<const float4*>(hrow + i);
                hreg[i] = v.x; hreg[i + 1] = v.y; hreg[i + 2] = v.z; hreg[i + 3] = v.w;
            }
            for (int slot = s0; slot < cnt; slot += 2) {
                int k = sclist[wv][row][slot];
                const float* wr = w + (size_t)k * DDIM;
                float acc = 0.f;
#pragma unroll
                for (int i = 0; i < DDIM; i += 4) {
                    float4 x = *reinterpret_cast<const float4*>(wr + i);
                    acc = fmaf(hreg[i + 0], x.x, acc);
                    acc = fmaf(hreg[i + 1], x.y, acc);
                    acc = fmaf(hreg[i + 2], x.z, acc);
                    acc = fmaf(hreg[i + 3], x.w, acc);
                }
                float d = __fsub_rn(__fadd_rn(Afr, bsq[k]), __fadd_rn(acc, acc));
                unsigned long long key = ((unsigned long long)fsort(d) << 32) | (unsigned)k;
                atomicMin(&sbkey[wv][row], key);
            }
        }
    }
    // overflow fallback (exact full scan, wave-wide; rare)
#pragma unroll 1
    for (int r = 0; r < RPW; ++r) {
        const float Afr = __shfl(af, r);
        if (scnt[wv][r] > CMAX) {
            const size_t ng = (size_t)rowbase + r;
            const float* hrow = h + ng * DDIM;
            float hreg[DDIM];
#pragma unroll
            for (int i = 0; i < DDIM; i += 4) {
                float4 v = *reinterpret_cast<const float4*>(hrow + i);
                hreg[i] = v.x; hreg[i + 1] = v.y; hreg[i + 2] = v.z; hreg[i + 3] = v.w;
            }
            for (int k = lane; k < KCB; k += 64) {
                const float* wr = w + (size_t)k * DDIM;
                float acc = 0.f;
#pragma unroll
                for (int i = 0; i < DDIM; i += 4) {
                    float4 x = *reinterpret_cast<const float4*>(wr + i);
                    acc = fmaf(hreg[i + 0], x.x, acc);
                    acc = fmaf(hreg[i + 1], x.y, acc);
                    acc = fmaf(hreg[i + 2], x.z, acc);
                    acc = fmaf(hreg[i + 3], x.w, acc);
                }
                float d = __fsub_rn(__fadd_rn(Afr, bsq[k]), __fadd_rn(acc, acc));
                unsigned long long key = ((unsigned long long)fsort(d) << 32) | (unsigned)k;
                atomicMin(&sbkey[wv][r], key);
            }
        }
    }
    __builtin_amdgcn_wave_barrier();

    // ---- fused outputs (per wave) — frozen R13/R14 ----
    if (lane < RPW)
        out[NQ + rowbase + lane] = (float)(unsigned)(sbkey[wv][lane] & 0xFFFFFFFFu);

#pragma unroll
    for (int q = 0; q < 8; ++q) {
        const int idx = q * 64 + lane;
        const int row = idx >> 4, c4 = idx & 15;
        const int bk = (int)(unsigned)(sbkey[wv][row] & 0xFFFFFFFFu);
        const size_t ng = (size_t)rowbase + row;
        float4 hq = *reinterpret_cast<const float4*>(h + ng * DDIM + 4 * c4);
        float4 wq = *reinterpret_cast<const float4*>(w + (size_t)bk * DDIM + 4 * c4);
        float4 o;
        o.x = __fadd_rn(hq.x, __fsub_rn(wq.x, hq.x));
        o.y = __fadd_rn(hq.y, __fsub_rn(wq.y, hq.y));
        o.z = __fadd_rn(hq.z, __fsub_rn(wq.z, hq.z));
        o.w = __fadd_rn(hq.w, __fsub_rn(wq.w, hq.w));
        *reinterpret_cast<float4*>(out + ng * DDIM + 4 * c4) = o;
    }

    if (lane < RPW) {
        const int bk = (int)(unsigned)(sbkey[wv][lane] & 0xFFFFFFFFu);
        const size_t ng = (size_t)rowbase + lane;
        const float* hrow = h + ng * DDIM;
        const float* qrow = w + (size_t)bk * DDIM;
        float hr[DDIM];
#pragma unroll
        for (int i = 0; i < DDIM; i += 4) {
            float4 v = *reinterpret_cast<const float4*>(hrow + i);
            hr[i] = v.x; hr[i + 1] = v.y; hr[i + 2] = v.z; hr[i + 3] = v.w;
        }
        float r2[8];
#pragma unroll
        for (int c = 0; c < 8; ++c) {
            float4 qa = *reinterpret_cast<const float4*>(qrow + 8 * c);
            float4 qb = *reinterpret_cast<const float4*>(qrow + 8 * c + 4);
            float d0 = __fsub_rn(qa.x, hr[8 * c + 0]);
            float d1 = __fsub_rn(qa.y, hr[8 * c + 1]);
            float d2 = __fsub_rn(qa.z, hr[8 * c + 2]);
            float d3 = __fsub_rn(qa.w, hr[8 * c + 3]);
            float d4 = __fsub_rn(qb.x, hr[8 * c + 4]);
            float d5 = __fsub_rn(qb.y, hr[8 * c + 5]);
            float d6 = __fsub_rn(qb.z, hr[8 * c + 6]);
            float d7 = __fsub_rn(qb.w, hr[8 * c + 7]);
            if (c == 0) {
                r2[0] = __fmul_rn(d0, d0); r2[1] = __fmul_rn(d1, d1);
                r2[2] = __fmul_rn(d2, d2); r2[3] = __fmul_rn(d3, d3);
                r2[4] = __fmul_rn(d4, d4); r2[5] = __fmul_rn(d5, d5);
                r2[6] = __fmul_rn(d6, d6); r2[7] = __fmul_rn(d7, d7);
            } else {
                r2[0] = __fadd_rn(r2[0], __fmul_rn(d0, d0));
                r2[1] = __fadd_rn(r2[1], __fmul_rn(d1, d1));
                r2[2] = __fadd_rn(r2[2], __fmul_rn(d2, d2));
                r2[3] = __fadd_rn(r2[3], __fmul_rn(d3, d3));
                r2[4] = __fadd_rn(r2[4], __fmul_rn(d4, d4));
                r2[5] = __fadd_rn(r2[5], __fmul_rn(d5, d5));
                r2[6] = __fadd_rn(r2[6], __fmul_rn(d6, d6));
                r2[7] = __fadd_rn(r2[7], __fmul_rn(d7, d7));
            }
        }
        float S = __fadd_rn(__fadd_rn(__fadd_rn(r2[0], r2[1]), __fadd_rn(r2[2], r2[3])),
                            __fadd_rn(__fadd_rn(r2[4], r2[5]), __fadd_rn(r2[6], r2[7])));
        float m = __fmul_rn(S, 0.015625f);
        out[NQ + NROWS + ng] = __fadd_rn(__fmul_rn(m, 0.1f), __fmul_rn(m, 0.2f));
    }
}

extern "C" void kernel_launch(void* const* d_in, const int* in_sizes, int n_in,
                              void* d_out, int out_size, void* d_ws, size_t ws_size,
                              hipStream_t stream) {
    (void)in_sizes; (void)n_in; (void)out_size; (void)ws_size;
    const float* h = (const float*)d_in[0];
    const float* w = (const float*)d_in[1];
    float* out = (float*)d_out;

    char* ws = (char*)d_ws;
    float* bsq = (float*)ws;                               // 4 KB
    float* wmaxp = (float*)(ws + 4096);                    // 16 B
    unsigned short* wbf = (unsigned short*)(ws + 8192);    // 128 KB

    prep_w<<<1, 1024, 0, stream>>>(w, bsq, wbf, wmaxp);
    vq_scan<<<NROWS / (WAVES * RPW), BLKT, 0, stream>>>(h, w, wbf, bsq, wmaxp, out);
}